// Round 8
// baseline (444.710 us; speedup 1.0000x reference)
//
#include <hip/hip_runtime.h>
#include <hip/hip_bf16.h>

#define HDIM 128
#define PAD 64
static constexpr float BN_S = 0.99999500003749968751f; // 1/sqrt(1+1e-5)

typedef float f32x4 __attribute__((ext_vector_type(4)));
typedef short s16x8 __attribute__((ext_vector_type(8)));

union U128 { uint4 u; s16x8 s; };

__device__ __forceinline__ unsigned short f2bs(float f){
    union{float f; unsigned u;} c; c.f = f;
    unsigned r = c.u + 0x7fffu + ((c.u >> 16) & 1u);
    return (unsigned short)(r >> 16);
}
__device__ __forceinline__ float bs2f(unsigned short s){
    union{unsigned u; float f;} c; c.u = ((unsigned)s) << 16;
    return c.f;
}
__device__ __forceinline__ float ulo(unsigned u){ union{unsigned i; float f;} c; c.i = u << 16; return c.f; }
__device__ __forceinline__ float uhi(unsigned u){ union{unsigned i; float f;} c; c.i = u & 0xffff0000u; return c.f; }

// ---------------- prepack all weights (weights only; ~456 blocks, fast) ----------------
__global__ __launch_bounds__(256) void k_prep(
    const float* __restrict__ linW, const float* __restrict__ cW1,
    const float* __restrict__ cW2, const float* __restrict__ cW3,
    const float* __restrict__ hW1, const float* __restrict__ oW1,
    const float* __restrict__ hW2, const float* __restrict__ oW2,
    unsigned short* __restrict__ wf, unsigned short* __restrict__ p1,
    unsigned short* __restrict__ p2)
{
    int id = blockIdx.x * 256 + threadIdx.x;
    if (id < 65536){
        int mat = id >> 14;
        int el = id & 16383;
        int k = el >> 7, n = el & 127;
        const float* W = (mat == 0) ? linW : (mat == 1) ? cW1 : (mat == 2) ? cW2 : cW3;
        float v = W[k * 128 + n];
        unsigned short hs = f2bs(v);
        unsigned short ls = f2bs(v - bs2f(hs));
        int nt = n >> 4, lanen = n & 15, kc = k >> 5, quad = (k >> 3) & 3, j = k & 7;
        int lane = quad * 16 + lanen;
        size_t base = (size_t)mat * 32768;
        wf[base + (size_t)(((nt * 4 + kc) * 2 + 0) * 64 + lane) * 8 + j] = hs;
        wf[base + (size_t)(((nt * 4 + kc) * 2 + 1) * 64 + lane) * 8 + j] = ls;
    } else if (id < 65536 + 51200){
        int id1 = id - 65536;
        if (id1 < 40960){
            int j = id1 & 7, lane = (id1 >> 3) & 63, kc = (id1 >> 9) & 3, nt = (id1 >> 11) & 3, y = id1 >> 13;
            int k = kc * 32 + (lane >> 4) * 8 + j;
            int n = nt * 16 + (lane & 15);
            float w = (y < 4) ? hW1[(y * 128 + k) * 64 + n] : oW1[k * 64 + n];
            p1[id1] = f2bs(w);
        } else {
            int id2 = id1 - 40960;
            int j = id2 & 7, lane = (id2 >> 3) & 63, kc = (id2 >> 9) & 1, nt = (id2 >> 10) & 1, y = id2 >> 11;
            int k = kc * 32 + (lane >> 4) * 8 + j;
            int n = nt * 16 + (lane & 15);
            float w = (y < 4) ? hW2[(y * 64 + k) * 32 + n] : oW2[k * 32 + n];
            p2[id2] = f2bs(w);
        }
    }
}

// ---------------- fused: gemm0+gemm1 blocks + INDEPENDENT edge count blocks ----------------
__global__ __launch_bounds__(256) void k_cg01e(
    const float* __restrict__ x, const uint4* __restrict__ wf0, const uint4* __restrict__ wf1,
    const float* __restrict__ ing, const float* __restrict__ inb,
    const float* __restrict__ lb, const float* __restrict__ g0, const float* __restrict__ b0,
    float* __restrict__ hout, unsigned short* __restrict__ hwout, int nrows, int gb,
    const int* __restrict__ esrc, const int* __restrict__ edst,
    int* __restrict__ cnt, unsigned short* __restrict__ slots, int E)
{
    __shared__ __align__(16) unsigned sbuf[64 * 136];
    int bid = blockIdx.x;
    int t = threadIdx.x;

    if (bid >= gb){
        int e = (bid - gb) * 256 + t;
        if (e < E){
            int d = edst[e];
            int r = atomicAdd(&cnt[d], 1);
            if (r < PAD) slots[(size_t)d * PAD + r] = (unsigned short)esrc[e];  // N < 65536
        }
        return;
    }

    unsigned* sAhi = sbuf;
    unsigned* sAlo = sbuf + 64 * 68;
    int row0 = bid * 64;
    for (int i = t; i < 2048; i += 256){
        int r = i >> 5, q = i & 31;
        int gr = row0 + r;
        float4 v = make_float4(0.f, 0.f, 0.f, 0.f);
        if (gr < nrows) v = *(const float4*)&x[(size_t)gr * 128 + q * 4];
        float4 g = *(const float4*)&ing[q * 4];
        float4 bo = *(const float4*)&inb[q * 4];
        v.x = v.x * (g.x * BN_S) + bo.x;
        v.y = v.y * (g.y * BN_S) + bo.y;
        v.z = v.z * (g.z * BN_S) + bo.z;
        v.w = v.w * (g.w * BN_S) + bo.w;
        unsigned u0 = __float_as_uint(v.x), u1 = __float_as_uint(v.y);
        unsigned u2 = __float_as_uint(v.z), u3 = __float_as_uint(v.w);
        uint2 hi = make_uint2((u0 >> 16) | (u1 & 0xffff0000u), (u2 >> 16) | (u3 & 0xffff0000u));
        unsigned short l0 = f2bs(v.x - __uint_as_float(u0 & 0xffff0000u));
        unsigned short l1 = f2bs(v.y - __uint_as_float(u1 & 0xffff0000u));
        unsigned short l2 = f2bs(v.z - __uint_as_float(u2 & 0xffff0000u));
        unsigned short l3 = f2bs(v.w - __uint_as_float(u3 & 0xffff0000u));
        uint2 lo = make_uint2((unsigned)l0 | ((unsigned)l1 << 16), (unsigned)l2 | ((unsigned)l3 << 16));
        *(uint2*)&sAhi[r * 68 + q * 2] = hi;
        *(uint2*)&sAlo[r * 68 + q * 2] = lo;
    }
    __syncthreads();

    int w = t >> 6, l = t & 63;
    int lanen = l & 15, quad = l >> 4;
    int mrow = w * 16 + lanen;
    f32x4 acc[8];
#pragma unroll
    for (int i = 0; i < 8; ++i) acc[i] = (f32x4){0.f, 0.f, 0.f, 0.f};

#pragma unroll 1
    for (int kc = 0; kc < 4; ++kc){
        U128 ahi, alo;
        ahi.u = *(const uint4*)&sAhi[mrow * 68 + kc * 16 + quad * 4];
        alo.u = *(const uint4*)&sAlo[mrow * 68 + kc * 16 + quad * 4];
        U128 whi[8];
#pragma unroll
        for (int nt = 0; nt < 8; ++nt)
            whi[nt].u = wf0[((nt * 4 + kc) * 2 + 0) * 64 + l];
#pragma unroll
        for (int nt = 0; nt < 8; ++nt)
            acc[nt] = __builtin_amdgcn_mfma_f32_16x16x32_bf16(ahi.s, whi[nt].s, acc[nt], 0, 0, 0);
#pragma unroll
        for (int nt = 0; nt < 8; ++nt)
            acc[nt] = __builtin_amdgcn_mfma_f32_16x16x32_bf16(alo.s, whi[nt].s, acc[nt], 0, 0, 0);
    }

    // epilogue gemm0: h tile -> LDS (f32, stride 132), coalesced fp32 global write
    __syncthreads();
    float* so = (float*)sbuf;
#pragma unroll
    for (int nt = 0; nt < 8; ++nt){
        int n = nt * 16 + lanen;
        float bias = lb[n], g = g0[n], bo = b0[n];
#pragma unroll
        for (int r = 0; r < 4; ++r){
            int row = w * 16 + quad * 4 + r;
            float v = g * ((acc[nt][r] + bias) * BN_S) + bo;
            so[row * 132 + n] = fmaxf(v, 0.f);
        }
    }
    __syncthreads();
    for (int i = t; i < 2048; i += 256){
        int row = i >> 5, c4 = (i & 31) * 4;
        int grow = row0 + row;
        if (grow < nrows)
            *(float4*)&hout[(size_t)grow * 128 + c4] = *(float4*)&so[row * 132 + c4];
    }

    // gemm1: fragments straight from so (h tile); UNSCALED bf16 out
    f32x4 acc2[8];
#pragma unroll
    for (int i = 0; i < 8; ++i) acc2[i] = (f32x4){0.f, 0.f, 0.f, 0.f};
#pragma unroll 1
    for (int kc = 0; kc < 4; ++kc){
        float4 a0 = *(const float4*)&so[mrow * 132 + kc * 32 + quad * 8];
        float4 a1 = *(const float4*)&so[mrow * 132 + kc * 32 + quad * 8 + 4];
        U128 af;
        af.u.x = (unsigned)f2bs(a0.x) | ((unsigned)f2bs(a0.y) << 16);
        af.u.y = (unsigned)f2bs(a0.z) | ((unsigned)f2bs(a0.w) << 16);
        af.u.z = (unsigned)f2bs(a1.x) | ((unsigned)f2bs(a1.y) << 16);
        af.u.w = (unsigned)f2bs(a1.z) | ((unsigned)f2bs(a1.w) << 16);
        U128 wh[8];
#pragma unroll
        for (int nt = 0; nt < 8; ++nt)
            wh[nt].u = wf1[((nt * 4 + kc) * 2 + 0) * 64 + l];
#pragma unroll
        for (int nt = 0; nt < 8; ++nt)
            acc2[nt] = __builtin_amdgcn_mfma_f32_16x16x32_bf16(af.s, wh[nt].s, acc2[nt], 0, 0, 0);
    }
    __syncthreads();   // all waves done reading so
    unsigned short* ss = (unsigned short*)sbuf;
#pragma unroll
    for (int nt = 0; nt < 8; ++nt){
        int n = nt * 16 + lanen;
#pragma unroll
        for (int r = 0; r < 4; ++r){
            int row = w * 16 + quad * 4 + r;
            ss[row * 136 + n] = f2bs(acc2[nt][r]);
        }
    }
    __syncthreads();
    for (int i = t; i < 1024; i += 256){
        int row = i >> 4, c = i & 15;
        int grow = row0 + row;
        if (grow < nrows)
            *(uint4*)&hwout[(size_t)grow * 128 + c * 8] = *(uint4*)&ss[row * 136 + c * 8];
    }
}

// ---------------- standalone layer gemm: bf16 h in, dis-prescaled bf16 out ----------------
__global__ __launch_bounds__(256) void k_gemmb(
    const uint4* __restrict__ hb16, const uint4* __restrict__ wf,
    const int* __restrict__ cnt,
    unsigned short* __restrict__ hwout, int nrows)
{
    __shared__ __align__(16) unsigned sbuf[64 * 68];
    __shared__ float sdis[64];
    int t = threadIdx.x;
    int row0 = blockIdx.x * 64;
    if (t < 64){
        int gr = row0 + t;
        sdis[t] = (gr < nrows) ? rsqrtf(1.0f + (float)cnt[gr]) : 1.0f;
    }
    for (int i = t; i < 1024; i += 256){
        int r = i >> 4, c = i & 15;
        int gr = row0 + r;
        uint4 v = make_uint4(0u, 0u, 0u, 0u);
        if (gr < nrows) v = hb16[(size_t)gr * 16 + c];
        *(uint4*)&sbuf[r * 68 + c * 4] = v;
    }
    __syncthreads();

    int w = t >> 6, l = t & 63;
    int lanen = l & 15, quad = l >> 4;
    int mrow = w * 16 + lanen;
    f32x4 acc[8];
#pragma unroll
    for (int i = 0; i < 8; ++i) acc[i] = (f32x4){0.f, 0.f, 0.f, 0.f};
#pragma unroll 1
    for (int kc = 0; kc < 4; ++kc){
        U128 ah;
        ah.u = *(const uint4*)&sbuf[mrow * 68 + kc * 16 + quad * 4];
        U128 wh[8];
#pragma unroll
        for (int nt = 0; nt < 8; ++nt)
            wh[nt].u = wf[((nt * 4 + kc) * 2 + 0) * 64 + l];
#pragma unroll
        for (int nt = 0; nt < 8; ++nt)
            acc[nt] = __builtin_amdgcn_mfma_f32_16x16x32_bf16(ah.s, wh[nt].s, acc[nt], 0, 0, 0);
    }
    __syncthreads();
    unsigned short* ss = (unsigned short*)sbuf;
#pragma unroll
    for (int nt = 0; nt < 8; ++nt){
        int n = nt * 16 + lanen;
#pragma unroll
        for (int r = 0; r < 4; ++r){
            int row = w * 16 + quad * 4 + r;
            ss[row * 136 + n] = f2bs(acc[nt][r] * sdis[row]);
        }
    }
    __syncthreads();
    for (int i = t; i < 1024; i += 256){
        int row = i >> 4, c = i & 15;
        int grow = row0 + row;
        if (grow < nrows)
            *(uint4*)&hwout[(size_t)grow * 128 + c * 8] = *(uint4*)&ss[row * 136 + c * 8];
    }
}

// ---------------- SLICED padded-slot aggregate ----------------
// Grid (rows/4, 4). Slice y handles output cols [32y, 32y+32): gathers only 64 B/row
// from a 3.2 MB table slice that fits a 4 MB per-XCD L2 (x-major dispatch keeps the
// resident window within one slice). Same slot order + reduction tree as before ->
// bitwise-identical results.
// SCALESRC=1 (layer 1): hwu rows UNSCALED, per-edge coef = dis[src]; self term *dis[row].
// WRITEH=1: write fp32 h (residual) + bf16 h; WRITEH=0 (final layer): bf16 h only.
template<int WRITEH, int SCALESRC>
__device__ __forceinline__ void agg_body(
    const unsigned* __restrict__ hwu, float* __restrict__ h,
    const int* __restrict__ cnt, const unsigned short* __restrict__ slots,
    const float* __restrict__ cb, const float* __restrict__ bg, const float* __restrict__ bb,
    unsigned* __restrict__ hb16o, int N)
{
    int row = blockIdx.x * 4 + (threadIdx.x >> 6);
    int y = blockIdx.y;
    if (row >= N) return;
    int l = threadIdx.x & 63;
    int sub = l >> 4, cg = l & 15;
    int c0 = cnt[row];
    int c = (c0 > PAD) ? PAD : c0;
    float a0 = 0.f, a1 = 0.f;
    for (int p = 0; p < c; p += 16){
        int base = p + sub * 4;
        if (base < c){
            uint2 s2 = *(const uint2*)&slots[(size_t)row * PAD + base];
            int s0 = (int)(s2.x & 0xffffu);
            int t1 = (int)(s2.x >> 16);
            int t2 = (int)(s2.y & 0xffffu);
            int t3 = (int)(s2.y >> 16);
            int i1 = (base + 1 < c) ? t1 : s0;
            int i2 = (base + 2 < c) ? t2 : s0;
            int i3 = (base + 3 < c) ? t3 : s0;
            float cf0, cf1, cf2, cf3;
            if (SCALESRC){
                cf0 = rsqrtf(1.0f + (float)cnt[s0]);
                cf1 = (base + 1 < c) ? rsqrtf(1.0f + (float)cnt[i1]) : 0.f;
                cf2 = (base + 2 < c) ? rsqrtf(1.0f + (float)cnt[i2]) : 0.f;
                cf3 = (base + 3 < c) ? rsqrtf(1.0f + (float)cnt[i3]) : 0.f;
            } else {
                cf0 = 1.f;
                cf1 = (base + 1 < c) ? 1.f : 0.f;
                cf2 = (base + 2 < c) ? 1.f : 0.f;
                cf3 = (base + 3 < c) ? 1.f : 0.f;
            }
            unsigned v0 = hwu[(size_t)s0 * 64 + y * 16 + cg];
            unsigned v1 = hwu[(size_t)i1 * 64 + y * 16 + cg];
            unsigned v2 = hwu[(size_t)i2 * 64 + y * 16 + cg];
            unsigned v3 = hwu[(size_t)i3 * 64 + y * 16 + cg];
            a0 = fmaf(ulo(v0), cf0, a0); a1 = fmaf(uhi(v0), cf0, a1);
            a0 = fmaf(ulo(v1), cf1, a0); a1 = fmaf(uhi(v1), cf1, a1);
            a0 = fmaf(ulo(v2), cf2, a0); a1 = fmaf(uhi(v2), cf2, a1);
            a0 = fmaf(ulo(v3), cf3, a0); a1 = fmaf(uhi(v3), cf3, a1);
        }
    }
    a0 += __shfl_xor(a0, 16); a0 += __shfl_xor(a0, 32);
    a1 += __shfl_xor(a1, 16); a1 += __shfl_xor(a1, 32);
    if (sub == 0){
        float d = rsqrtf(1.0f + (float)c0);
        float selfs = SCALESRC ? d : 1.f;
        unsigned sv = hwu[(size_t)row * 64 + y * 16 + cg];
        int n0 = y * 32 + cg * 2;
        float2 ccv = *(const float2*)&cb[n0];
        float2 ggv = *(const float2*)&bg[n0];
        float2 bov = *(const float2*)&bb[n0];
        float2 cur = *(const float2*)&h[(size_t)row * 128 + n0];
        float v0 = ggv.x * (((a0 + ulo(sv) * selfs) * d + ccv.x) * BN_S) + bov.x;
        float v1 = ggv.y * (((a1 + uhi(sv) * selfs) * d + ccv.y) * BN_S) + bov.y;
        float o0 = cur.x + fmaxf(v0, 0.f);
        float o1 = cur.y + fmaxf(v1, 0.f);
        if (WRITEH)
            *(float2*)&h[(size_t)row * 128 + n0] = make_float2(o0, o1);
        hb16o[(size_t)row * 64 + y * 16 + cg] =
            (unsigned)f2bs(o0) | ((unsigned)f2bs(o1) << 16);
    }
}

__global__ __launch_bounds__(256) void k_agg1(
    const unsigned* __restrict__ hwu, float* __restrict__ h,
    const int* __restrict__ cnt, const unsigned short* __restrict__ slots,
    const float* __restrict__ cb, const float* __restrict__ bg, const float* __restrict__ bb,
    unsigned* __restrict__ hb16o, int N)
{
    agg_body<1, 1>(hwu, h, cnt, slots, cb, bg, bb, hb16o, N);
}

__global__ __launch_bounds__(256) void k_agg(
    const unsigned* __restrict__ hwu, float* __restrict__ h,
    const int* __restrict__ cnt, const unsigned short* __restrict__ slots,
    const float* __restrict__ cb, const float* __restrict__ bg, const float* __restrict__ bb,
    unsigned* __restrict__ hb16o, int N)
{
    agg_body<1, 0>(hwu, h, cnt, slots, cb, bg, bb, hb16o, N);
}

__global__ __launch_bounds__(256) void k_agg3(
    const unsigned* __restrict__ hwu, float* __restrict__ h,
    const int* __restrict__ cnt, const unsigned short* __restrict__ slots,
    const float* __restrict__ cb, const float* __restrict__ bg, const float* __restrict__ bb,
    unsigned* __restrict__ hb16o, int N)
{
    agg_body<0, 0>(hwu, h, cnt, slots, cb, bg, bb, hb16o, N);
}

// ---------------- MFMA fused heads: 2D grid (y = head), bf16 gather ----------------
__global__ __launch_bounds__(256) void k_headmm(
    const uint4* __restrict__ hb16, const int* __restrict__ gidx,
    const uint4* __restrict__ p1v, const uint4* __restrict__ p2v,
    const float* __restrict__ hb1, const float* __restrict__ hg1, const float* __restrict__ hbb1,
    const float* __restrict__ hb2,
    const float* __restrict__ hW3, const float* __restrict__ hb3,
    const float* __restrict__ ob1, const float* __restrict__ og1, const float* __restrict__ obb1,
    const float* __restrict__ ob2, const float* __restrict__ og2, const float* __restrict__ obb2,
    const float* __restrict__ oW3, const float* __restrict__ ob3,
    float* __restrict__ out, int G)
{
    __shared__ __align__(16) unsigned sxg[64 * 68];
    __shared__ __align__(16) unsigned sz1u[64 * 36];
    __shared__ __align__(16) unsigned sz2u[64 * 20];
    __shared__ float sb1[64], sg1[64], sbb1[64];
    __shared__ float sb2[32], sg2[32], sbb2[32];
    __shared__ float sW3[96];
    __shared__ float sb3[3];
    __shared__ int sgi[64];

    int t = threadIdx.x;
    int gblk = blockIdx.x;
    int y = blockIdx.y;
    bool bn2 = (y == 4);
    int w = t >> 6, l = t & 63;
    int lanen = l & 15, quad = l >> 4;

    const float* b1  = bn2 ? ob1  : (hb1 + y * 64);
    const float* g1  = bn2 ? og1  : (hg1 + y * 64);
    const float* bb1 = bn2 ? obb1 : (hbb1 + y * 64);
    const float* b2  = bn2 ? ob2  : (hb2 + y * 32);
    const float* W3  = bn2 ? oW3  : (hW3 + y * 32);
    const float* b3  = bn2 ? ob3  : (hb3 + y);
    int nc3 = bn2 ? 3 : 1;

    if (t < 64){
        sb1[t] = b1[t]; sg1[t] = g1[t]; sbb1[t] = bb1[t];
        if (t < 3) sb3[t] = (t < nc3) ? b3[t] : 0.f;
    } else if (t < 96){
        int p = t - 64;
        sb2[p] = b2[p];
        sg2[p] = bn2 ? og2[p] : 1.f;
        sbb2[p] = bn2 ? obb2[p] : 0.f;
    } else if (t < 192){
        int i = t - 96;
        sW3[i] = (i < 32 * nc3) ? W3[i] : 0.f;
    } else {
        int r = t - 192;
        int g = gblk * 64 + r;
        sgi[r] = (g < G) ? gidx[g] : 0;
    }
    __syncthreads();
    for (int i = t; i < 1024; i += 256){
        int r = i >> 4, c = i & 15;
        int node = sgi[r];
        uint4 v = hb16[(size_t)node * 16 + c];
        *(uint4*)&sxg[r * 68 + c * 4] = v;
    }
    __syncthreads();

    f32x4 acc1[4] = {{0.f,0.f,0.f,0.f},{0.f,0.f,0.f,0.f},{0.f,0.f,0.f,0.f},{0.f,0.f,0.f,0.f}};
#pragma unroll
    for (int kc = 0; kc < 4; ++kc){
        U128 a;
        a.u = *(const uint4*)&sxg[(w * 16 + lanen) * 68 + kc * 16 + quad * 4];
#pragma unroll
        for (int nt = 0; nt < 4; ++nt){
            U128 bfr;
            bfr.u = p1v[((y * 4 + nt) * 4 + kc) * 64 + l];
            acc1[nt] = __builtin_amdgcn_mfma_f32_16x16x32_bf16(a.s, bfr.s, acc1[nt], 0, 0, 0);
        }
    }
    {
        unsigned short* sz1s = (unsigned short*)sz1u;
#pragma unroll
        for (int nt = 0; nt < 4; ++nt){
            int n = nt * 16 + lanen;
            float g = sg1[n], bia = sb1[n], bt = sbb1[n];
#pragma unroll
            for (int r = 0; r < 4; ++r){
                int row = w * 16 + quad * 4 + r;
                float v = g * ((acc1[nt][r] + bia) * BN_S) + bt;
                sz1s[row * 72 + n] = f2bs(fmaxf(v, 0.f));
            }
        }
    }
    __syncthreads();

    f32x4 acc2[2] = {{0.f,0.f,0.f,0.f},{0.f,0.f,0.f,0.f}};
#pragma unroll
    for (int kc = 0; kc < 2; ++kc){
        U128 a;
        a.u = *(const uint4*)&sz1u[(w * 16 + lanen) * 36 + kc * 16 + quad * 4];
#pragma unroll
        for (int nt = 0; nt < 2; ++nt){
            U128 bfr;
            bfr.u = p2v[((y * 2 + nt) * 2 + kc) * 64 + l];
            acc2[nt] = __builtin_amdgcn_mfma_f32_16x16x32_bf16(a.s, bfr.s, acc2[nt], 0, 0, 0);
        }
    }
    {
        unsigned short* sz2s = (unsigned short*)sz2u;
#pragma unroll
        for (int nt = 0; nt < 2; ++nt){
            int n = nt * 16 + lanen;
            float bia = sb2[n], g = sg2[n], bt = sbb2[n];
#pragma unroll
            for (int r = 0; r < 4; ++r){
                int row = w * 16 + quad * 4 + r;
                float v = acc2[nt][r] + bia;
                if (bn2) v = g * (v * BN_S) + bt;
                sz2s[row * 40 + n] = f2bs(fmaxf(v, 0.f));
            }
        }
    }
    __syncthreads();

    const unsigned short* sz2s = (const unsigned short*)sz2u;
    if (!bn2){
        if (t < 64){
            int g = gblk * 64 + t;
            if (g < G){
                float s = sb3[0];
#pragma unroll
                for (int p = 0; p < 32; ++p) s = fmaf(bs2f(sz2s[t * 40 + p]), sW3[p], s);
                out[(size_t)g * 7 + y] = s;
            }
        }
    } else {
        if (t < 192){
            int gl = t / 3, c = t % 3;
            int g = gblk * 64 + gl;
            if (g < G){
                float s = sb3[c];
#pragma unroll
                for (int p = 0; p < 32; ++p) s = fmaf(bs2f(sz2s[gl * 40 + p]), sW3[p * 3 + c], s);
                out[(size_t)g * 7 + 4 + c] = s;
            }
        }
    }
}

extern "C" void kernel_launch(void* const* d_in, const int* in_sizes, int n_in,
                              void* d_out, int out_size, void* d_ws, size_t ws_size,
                              hipStream_t stream)
{
    const float* x    = (const float*)d_in[0];
    const int* esrc   = (const int*)d_in[1];
    const int* edst   = (const int*)d_in[2];
    const int* gidx   = (const int*)d_in[3];
    const float* in_g = (const float*)d_in[4];
    const float* in_b = (const float*)d_in[5];
    const float* lin_W = (const float*)d_in[6];
    const float* lin_b = (const float*)d_in[7];
    const float* bn0_g = (const float*)d_in[8];
    const float* bn0_b = (const float*)d_in[9];
    const float* cW[3] = {(const float*)d_in[10], (const float*)d_in[14], (const float*)d_in[18]};
    const float* cb[3] = {(const float*)d_in[11], (const float*)d_in[15], (const float*)d_in[19]};
    const float* bg[3] = {(const float*)d_in[12], (const float*)d_in[16], (const float*)d_in[20]};
    const float* bb[3] = {(const float*)d_in[13], (const float*)d_in[17], (const float*)d_in[21]};
    const float* hW1 = (const float*)d_in[22];
    const float* hb1 = (const float*)d_in[23];
    const float* hg1 = (const float*)d_in[24];
    const float* hbb1 = (const float*)d_in[25];
    const float* hW2 = (const float*)d_in[26];
    const float* hb2 = (const float*)d_in[27];
    const float* hW3 = (const float*)d_in[28];
    const float* hb3 = (const float*)d_in[29];
    const float* oW1 = (const float*)d_in[30];
    const float* ob1 = (const float*)d_in[31];
    const float* og1 = (const float*)d_in[32];
    const float* obb1 = (const float*)d_in[33];
    const float* oW2 = (const float*)d_in[34];
    const float* ob2 = (const float*)d_in[35];
    const float* og2 = (const float*)d_in[36];
    const float* obb2 = (const float*)d_in[37];
    const float* oW3 = (const float*)d_in[38];
    const float* ob3 = (const float*)d_in[39];

    const int N = in_sizes[0] / HDIM;
    const int E = in_sizes[1];
    const int G = in_sizes[3];

    char* wsp = (char*)d_ws;
    size_t off = 0;
    auto alloc = [&](size_t bytes) -> char* {
        char* p = wsp + off;
        off = (off + bytes + 255) & ~(size_t)255;
        return p;
    };
    int* cnt      = (int*)alloc((size_t)N * 4);
    unsigned short* slots = (unsigned short*)alloc((size_t)N * PAD * 2);
    float* hbuf   = (float*)alloc((size_t)N * HDIM * 4);
    unsigned short* hwbA = (unsigned short*)alloc((size_t)N * HDIM * 2);
    unsigned short* hwbB = (unsigned short*)alloc((size_t)N * HDIM * 2);
    unsigned short* hb16 = (unsigned short*)alloc((size_t)N * HDIM * 2);
    unsigned short* p1 = (unsigned short*)alloc(40960 * 2);
    unsigned short* p2 = (unsigned short*)alloc(10240 * 2);
    unsigned short* wf = (unsigned short*)alloc((size_t)4 * 32768 * 2);

    int gb = (N + 63) / 64;
    int nCB = (E + 255) / 256;

    // 0: zero counters
    hipMemsetAsync(cnt, 0, (size_t)N * 4, stream);
    // 1: prepack weights
    k_prep<<<dim3((65536 + 51200 + 255) / 256), dim3(256), 0, stream>>>(
        lin_W, cW[0], cW[1], cW[2], hW1, oW1, hW2, oW2, wf, p1, p2);
    // 2: fused gemm0+gemm1 (UNSCALED hwbA) + independent edge count blocks (no waiting)
    k_cg01e<<<dim3(gb + nCB), dim3(256), 0, stream>>>(
        x, (const uint4*)wf, (const uint4*)(wf + (size_t)32768),
        in_g, in_b, lin_b, bn0_g, bn0_b, hbuf, hwbA, N, gb,
        esrc, edst, cnt, slots, E);
    // 3: agg layer-1, column-sliced (scales gathered rows by dis[src]) -> h1 (fp32 + bf16)
    k_agg1<<<dim3((N + 3) / 4, 4), dim3(256), 0, stream>>>(
        (const unsigned*)hwbA, hbuf, cnt, slots, cb[0], bg[0], bb[0], (unsigned*)hb16, N);
    // 4: gemm layer-2 (dis-prescaled; cnt ready)
    k_gemmb<<<dim3(gb), dim3(256), 0, stream>>>(
        (const uint4*)hb16, (const uint4*)(wf + (size_t)2 * 32768), cnt, hwbB, N);
    // 5: agg layer-2, column-sliced -> h2
    k_agg<<<dim3((N + 3) / 4, 4), dim3(256), 0, stream>>>(
        (const unsigned*)hwbB, hbuf, cnt, slots, cb[1], bg[1], bb[1], (unsigned*)hb16, N);
    // 6: gemm layer-3
    k_gemmb<<<dim3(gb), dim3(256), 0, stream>>>(
        (const uint4*)hb16, (const uint4*)(wf + (size_t)3 * 32768), cnt, hwbA, N);
    // 7: agg layer-3, column-sliced -> bf16 h3 only
    k_agg3<<<dim3((N + 3) / 4, 4), dim3(256), 0, stream>>>(
        (const unsigned*)hwbA, hbuf, cnt, slots, cb[2], bg[2], bb[2], (unsigned*)hb16, N);
    // 8: heads — 2D grid, 5 heads x 256 game-blocks
    k_headmm<<<dim3((G + 63) / 64, 5), dim3(256), 0, stream>>>(
        (const uint4*)hb16, gidx, (const uint4*)p1, (const uint4*)p2,
        hb1, hg1, hbb1, hb2, hW3, hb3,
        ob1, og1, obb1, ob2, og2, obb2, oW3, ob3,
        (float*)d_out, G);
}

// Round 9
// 327.980 us; speedup vs baseline: 1.3559x; 1.3559x over previous
//
#include <hip/hip_runtime.h>
#include <hip/hip_bf16.h>

#define HDIM 128
#define PAD 64
static constexpr float BN_S = 0.99999500003749968751f; // 1/sqrt(1+1e-5)

typedef float f32x4 __attribute__((ext_vector_type(4)));
typedef short s16x8 __attribute__((ext_vector_type(8)));

union U128 { uint4 u; s16x8 s; };

__device__ __forceinline__ unsigned short f2bs(float f){
    union{float f; unsigned u;} c; c.f = f;
    unsigned r = c.u + 0x7fffu + ((c.u >> 16) & 1u);
    return (unsigned short)(r >> 16);
}
__device__ __forceinline__ float bs2f(unsigned short s){
    union{unsigned u; float f;} c; c.u = ((unsigned)s) << 16;
    return c.f;
}
__device__ __forceinline__ float ulo(unsigned u){ union{unsigned i; float f;} c; c.i = u << 16; return c.f; }
__device__ __forceinline__ float uhi(unsigned u){ union{unsigned i; float f;} c; c.i = u & 0xffff0000u; return c.f; }

// ---------------- prepack all weights + zero cnt (memset folded in) ----------------
__global__ __launch_bounds__(256) void k_prep(
    const float* __restrict__ linW, const float* __restrict__ cW1,
    const float* __restrict__ cW2, const float* __restrict__ cW3,
    const float* __restrict__ hW1, const float* __restrict__ oW1,
    const float* __restrict__ hW2, const float* __restrict__ oW2,
    unsigned short* __restrict__ wf, unsigned short* __restrict__ p1,
    unsigned short* __restrict__ p2, int* __restrict__ cnt, int N)
{
    int id = blockIdx.x * 256 + threadIdx.x;
    if (id < 65536){
        int mat = id >> 14;
        int el = id & 16383;
        int k = el >> 7, n = el & 127;
        const float* W = (mat == 0) ? linW : (mat == 1) ? cW1 : (mat == 2) ? cW2 : cW3;
        float v = W[k * 128 + n];
        unsigned short hs = f2bs(v);
        unsigned short ls = f2bs(v - bs2f(hs));
        int nt = n >> 4, lanen = n & 15, kc = k >> 5, quad = (k >> 3) & 3, j = k & 7;
        int lane = quad * 16 + lanen;
        size_t base = (size_t)mat * 32768;
        wf[base + (size_t)(((nt * 4 + kc) * 2 + 0) * 64 + lane) * 8 + j] = hs;
        wf[base + (size_t)(((nt * 4 + kc) * 2 + 1) * 64 + lane) * 8 + j] = ls;
    } else if (id < 65536 + 51200){
        int id1 = id - 65536;
        if (id1 < 40960){
            int j = id1 & 7, lane = (id1 >> 3) & 63, kc = (id1 >> 9) & 3, nt = (id1 >> 11) & 3, y = id1 >> 13;
            int k = kc * 32 + (lane >> 4) * 8 + j;
            int n = nt * 16 + (lane & 15);
            float w = (y < 4) ? hW1[(y * 128 + k) * 64 + n] : oW1[k * 64 + n];
            p1[id1] = f2bs(w);
        } else {
            int id2 = id1 - 40960;
            int j = id2 & 7, lane = (id2 >> 3) & 63, kc = (id2 >> 9) & 1, nt = (id2 >> 10) & 1, y = id2 >> 11;
            int k = kc * 32 + (lane >> 4) * 8 + j;
            int n = nt * 16 + (lane & 15);
            float w = (y < 4) ? hW2[(y * 64 + k) * 32 + n] : oW2[k * 32 + n];
            p2[id2] = f2bs(w);
        }
    } else {
        int z = id - (65536 + 51200);
        if (z < N) cnt[z] = 0;
    }
}

// ---------------- fused: INDEPENDENT edge count blocks (first) + gemm0+gemm1 blocks ----------------
// bid < nCB:  count blocks (dispatched first so their atomic latency hides under the
//             whole gemm stream), 1 edge/thread: rank = atomicAdd(cnt[dst]);
//             slots16[dst*PAD+rank] = (ushort)src. No dependence on gemm.
// bid >= nCB: gemm tile. gemm0 (split-A) -> fp32 h; gemm1 (bf16) -> UNSCALED bf16 hwout.
//             No dependence on cnt/slots. No inter-block waiting (round-6 lesson).
__global__ __launch_bounds__(256) void k_cg01e(
    const float* __restrict__ x, const uint4* __restrict__ wf0, const uint4* __restrict__ wf1,
    const float* __restrict__ ing, const float* __restrict__ inb,
    const float* __restrict__ lb, const float* __restrict__ g0, const float* __restrict__ b0,
    float* __restrict__ hout, unsigned short* __restrict__ hwout, int nrows, int nCB,
    const int* __restrict__ esrc, const int* __restrict__ edst,
    int* __restrict__ cnt, unsigned short* __restrict__ slots, int E)
{
    __shared__ __align__(16) unsigned sbuf[64 * 136];
    int bid = blockIdx.x;
    int t = threadIdx.x;

    if (bid < nCB){
        int e = bid * 256 + t;
        if (e < E){
            int d = edst[e];
            int r = atomicAdd(&cnt[d], 1);
            if (r < PAD) slots[(size_t)d * PAD + r] = (unsigned short)esrc[e];  // N < 65536
        }
        return;
    }

    unsigned* sAhi = sbuf;
    unsigned* sAlo = sbuf + 64 * 68;
    int row0 = (bid - nCB) * 64;
    for (int i = t; i < 2048; i += 256){
        int r = i >> 5, q = i & 31;
        int gr = row0 + r;
        float4 v = make_float4(0.f, 0.f, 0.f, 0.f);
        if (gr < nrows) v = *(const float4*)&x[(size_t)gr * 128 + q * 4];
        float4 g = *(const float4*)&ing[q * 4];
        float4 bo = *(const float4*)&inb[q * 4];
        v.x = v.x * (g.x * BN_S) + bo.x;
        v.y = v.y * (g.y * BN_S) + bo.y;
        v.z = v.z * (g.z * BN_S) + bo.z;
        v.w = v.w * (g.w * BN_S) + bo.w;
        unsigned u0 = __float_as_uint(v.x), u1 = __float_as_uint(v.y);
        unsigned u2 = __float_as_uint(v.z), u3 = __float_as_uint(v.w);
        uint2 hi = make_uint2((u0 >> 16) | (u1 & 0xffff0000u), (u2 >> 16) | (u3 & 0xffff0000u));
        unsigned short l0 = f2bs(v.x - __uint_as_float(u0 & 0xffff0000u));
        unsigned short l1 = f2bs(v.y - __uint_as_float(u1 & 0xffff0000u));
        unsigned short l2 = f2bs(v.z - __uint_as_float(u2 & 0xffff0000u));
        unsigned short l3 = f2bs(v.w - __uint_as_float(u3 & 0xffff0000u));
        uint2 lo = make_uint2((unsigned)l0 | ((unsigned)l1 << 16), (unsigned)l2 | ((unsigned)l3 << 16));
        *(uint2*)&sAhi[r * 68 + q * 2] = hi;
        *(uint2*)&sAlo[r * 68 + q * 2] = lo;
    }
    __syncthreads();

    int w = t >> 6, l = t & 63;
    int lanen = l & 15, quad = l >> 4;
    int mrow = w * 16 + lanen;
    f32x4 acc[8];
#pragma unroll
    for (int i = 0; i < 8; ++i) acc[i] = (f32x4){0.f, 0.f, 0.f, 0.f};

#pragma unroll 1
    for (int kc = 0; kc < 4; ++kc){
        U128 ahi, alo;
        ahi.u = *(const uint4*)&sAhi[mrow * 68 + kc * 16 + quad * 4];
        alo.u = *(const uint4*)&sAlo[mrow * 68 + kc * 16 + quad * 4];
        U128 whi[8];
#pragma unroll
        for (int nt = 0; nt < 8; ++nt)
            whi[nt].u = wf0[((nt * 4 + kc) * 2 + 0) * 64 + l];
#pragma unroll
        for (int nt = 0; nt < 8; ++nt)
            acc[nt] = __builtin_amdgcn_mfma_f32_16x16x32_bf16(ahi.s, whi[nt].s, acc[nt], 0, 0, 0);
#pragma unroll
        for (int nt = 0; nt < 8; ++nt)
            acc[nt] = __builtin_amdgcn_mfma_f32_16x16x32_bf16(alo.s, whi[nt].s, acc[nt], 0, 0, 0);
    }

    // epilogue gemm0: h tile -> LDS (f32, stride 132), coalesced fp32 global write
    __syncthreads();
    float* so = (float*)sbuf;
#pragma unroll
    for (int nt = 0; nt < 8; ++nt){
        int n = nt * 16 + lanen;
        float bias = lb[n], g = g0[n], bo = b0[n];
#pragma unroll
        for (int r = 0; r < 4; ++r){
            int row = w * 16 + quad * 4 + r;
            float v = g * ((acc[nt][r] + bias) * BN_S) + bo;
            so[row * 132 + n] = fmaxf(v, 0.f);
        }
    }
    __syncthreads();
    for (int i = t; i < 2048; i += 256){
        int row = i >> 5, c4 = (i & 31) * 4;
        int grow = row0 + row;
        if (grow < nrows)
            *(float4*)&hout[(size_t)grow * 128 + c4] = *(float4*)&so[row * 132 + c4];
    }

    // gemm1: fragments straight from so (h tile); UNSCALED bf16 out
    f32x4 acc2[8];
#pragma unroll
    for (int i = 0; i < 8; ++i) acc2[i] = (f32x4){0.f, 0.f, 0.f, 0.f};
#pragma unroll 1
    for (int kc = 0; kc < 4; ++kc){
        float4 a0 = *(const float4*)&so[mrow * 132 + kc * 32 + quad * 8];
        float4 a1 = *(const float4*)&so[mrow * 132 + kc * 32 + quad * 8 + 4];
        U128 af;
        af.u.x = (unsigned)f2bs(a0.x) | ((unsigned)f2bs(a0.y) << 16);
        af.u.y = (unsigned)f2bs(a0.z) | ((unsigned)f2bs(a0.w) << 16);
        af.u.z = (unsigned)f2bs(a1.x) | ((unsigned)f2bs(a1.y) << 16);
        af.u.w = (unsigned)f2bs(a1.z) | ((unsigned)f2bs(a1.w) << 16);
        U128 wh[8];
#pragma unroll
        for (int nt = 0; nt < 8; ++nt)
            wh[nt].u = wf1[((nt * 4 + kc) * 2 + 0) * 64 + l];
#pragma unroll
        for (int nt = 0; nt < 8; ++nt)
            acc2[nt] = __builtin_amdgcn_mfma_f32_16x16x32_bf16(af.s, wh[nt].s, acc2[nt], 0, 0, 0);
    }
    __syncthreads();   // all waves done reading so
    unsigned short* ss = (unsigned short*)sbuf;
#pragma unroll
    for (int nt = 0; nt < 8; ++nt){
        int n = nt * 16 + lanen;
#pragma unroll
        for (int r = 0; r < 4; ++r){
            int row = w * 16 + quad * 4 + r;
            ss[row * 136 + n] = f2bs(acc2[nt][r]);
        }
    }
    __syncthreads();
    for (int i = t; i < 1024; i += 256){
        int row = i >> 4, c = i & 15;
        int grow = row0 + row;
        if (grow < nrows)
            *(uint4*)&hwout[(size_t)grow * 128 + c * 8] = *(uint4*)&ss[row * 136 + c * 8];
    }
}

// ---------------- standalone layer gemm: bf16 h in, dis-prescaled bf16 out ----------------
__global__ __launch_bounds__(256) void k_gemmb(
    const uint4* __restrict__ hb16, const uint4* __restrict__ wf,
    const int* __restrict__ cnt,
    unsigned short* __restrict__ hwout, int nrows)
{
    __shared__ __align__(16) unsigned sbuf[64 * 68];
    __shared__ float sdis[64];
    int t = threadIdx.x;
    int row0 = blockIdx.x * 64;
    if (t < 64){
        int gr = row0 + t;
        sdis[t] = (gr < nrows) ? rsqrtf(1.0f + (float)cnt[gr]) : 1.0f;
    }
    for (int i = t; i < 1024; i += 256){
        int r = i >> 4, c = i & 15;
        int gr = row0 + r;
        uint4 v = make_uint4(0u, 0u, 0u, 0u);
        if (gr < nrows) v = hb16[(size_t)gr * 16 + c];
        *(uint4*)&sbuf[r * 68 + c * 4] = v;
    }
    __syncthreads();

    int w = t >> 6, l = t & 63;
    int lanen = l & 15, quad = l >> 4;
    int mrow = w * 16 + lanen;
    f32x4 acc[8];
#pragma unroll
    for (int i = 0; i < 8; ++i) acc[i] = (f32x4){0.f, 0.f, 0.f, 0.f};
#pragma unroll 1
    for (int kc = 0; kc < 4; ++kc){
        U128 ah;
        ah.u = *(const uint4*)&sbuf[mrow * 68 + kc * 16 + quad * 4];
        U128 wh[8];
#pragma unroll
        for (int nt = 0; nt < 8; ++nt)
            wh[nt].u = wf[((nt * 4 + kc) * 2 + 0) * 64 + l];
#pragma unroll
        for (int nt = 0; nt < 8; ++nt)
            acc[nt] = __builtin_amdgcn_mfma_f32_16x16x32_bf16(ah.s, wh[nt].s, acc[nt], 0, 0, 0);
    }
    __syncthreads();
    unsigned short* ss = (unsigned short*)sbuf;
#pragma unroll
    for (int nt = 0; nt < 8; ++nt){
        int n = nt * 16 + lanen;
#pragma unroll
        for (int r = 0; r < 4; ++r){
            int row = w * 16 + quad * 4 + r;
            ss[row * 136 + n] = f2bs(acc[nt][r] * sdis[row]);
        }
    }
    __syncthreads();
    for (int i = t; i < 1024; i += 256){
        int row = i >> 4, c = i & 15;
        int grow = row0 + row;
        if (grow < nrows)
            *(uint4*)&hwout[(size_t)grow * 128 + c * 8] = *(uint4*)&ss[row * 136 + c * 8];
    }
}

// ---------------- padded-slot aggregate (full-row; r7 proven form) ----------------
// SCALESRC=1 (layer 1): hwu rows UNSCALED, per-edge coef = dis[src]; self term *dis[row].
// WRITEH=1: write fp32 h (residual) + bf16 h; WRITEH=0 (final layer): bf16 h only.
template<int WRITEH, int SCALESRC>
__device__ __forceinline__ void agg_body(
    const unsigned* __restrict__ hwu, float* __restrict__ h,
    const int* __restrict__ cnt, const unsigned short* __restrict__ slots,
    const float* __restrict__ cb, const float* __restrict__ bg, const float* __restrict__ bb,
    uint4* __restrict__ hb16o, int N)
{
    int row = blockIdx.x * 4 + (threadIdx.x >> 6);
    if (row >= N) return;
    int l = threadIdx.x & 63;
    int sub = l >> 4, cg = l & 15;
    int c0 = cnt[row];
    int c = (c0 > PAD) ? PAD : c0;
    float acc[8];
#pragma unroll
    for (int i = 0; i < 8; ++i) acc[i] = 0.f;
    for (int p = 0; p < c; p += 16){
        int base = p + sub * 4;
        if (base < c){
            uint2 s2 = *(const uint2*)&slots[(size_t)row * PAD + base];
            int s0 = (int)(s2.x & 0xffffu);
            int t1 = (int)(s2.x >> 16);
            int t2 = (int)(s2.y & 0xffffu);
            int t3 = (int)(s2.y >> 16);
            int i1 = (base + 1 < c) ? t1 : s0;
            int i2 = (base + 2 < c) ? t2 : s0;
            int i3 = (base + 3 < c) ? t3 : s0;
            float cf0, cf1, cf2, cf3;
            if (SCALESRC){
                cf0 = rsqrtf(1.0f + (float)cnt[s0]);
                cf1 = (base + 1 < c) ? rsqrtf(1.0f + (float)cnt[i1]) : 0.f;
                cf2 = (base + 2 < c) ? rsqrtf(1.0f + (float)cnt[i2]) : 0.f;
                cf3 = (base + 3 < c) ? rsqrtf(1.0f + (float)cnt[i3]) : 0.f;
            } else {
                cf0 = 1.f;
                cf1 = (base + 1 < c) ? 1.f : 0.f;
                cf2 = (base + 2 < c) ? 1.f : 0.f;
                cf3 = (base + 3 < c) ? 1.f : 0.f;
            }
            uint4 v0 = *(const uint4*)&hwu[(size_t)s0 * 64 + cg * 4];
            uint4 v1 = *(const uint4*)&hwu[(size_t)i1 * 64 + cg * 4];
            uint4 v2 = *(const uint4*)&hwu[(size_t)i2 * 64 + cg * 4];
            uint4 v3 = *(const uint4*)&hwu[(size_t)i3 * 64 + cg * 4];
            acc[0] = fmaf(ulo(v0.x), cf0, acc[0]); acc[1] = fmaf(uhi(v0.x), cf0, acc[1]);
            acc[2] = fmaf(ulo(v0.y), cf0, acc[2]); acc[3] = fmaf(uhi(v0.y), cf0, acc[3]);
            acc[4] = fmaf(ulo(v0.z), cf0, acc[4]); acc[5] = fmaf(uhi(v0.z), cf0, acc[5]);
            acc[6] = fmaf(ulo(v0.w), cf0, acc[6]); acc[7] = fmaf(uhi(v0.w), cf0, acc[7]);
            acc[0] = fmaf(ulo(v1.x), cf1, acc[0]); acc[1] = fmaf(uhi(v1.x), cf1, acc[1]);
            acc[2] = fmaf(ulo(v1.y), cf1, acc[2]); acc[3] = fmaf(uhi(v1.y), cf1, acc[3]);
            acc[4] = fmaf(ulo(v1.z), cf1, acc[4]); acc[5] = fmaf(uhi(v1.z), cf1, acc[5]);
            acc[6] = fmaf(ulo(v1.w), cf1, acc[6]); acc[7] = fmaf(uhi(v1.w), cf1, acc[7]);
            acc[0] = fmaf(ulo(v2.x), cf2, acc[0]); acc[1] = fmaf(uhi(v2.x), cf2, acc[1]);
            acc[2] = fmaf(ulo(v2.y), cf2, acc[2]); acc[3] = fmaf(uhi(v2.y), cf2, acc[3]);
            acc[4] = fmaf(ulo(v2.z), cf2, acc[4]); acc[5] = fmaf(uhi(v2.z), cf2, acc[5]);
            acc[6] = fmaf(ulo(v2.w), cf2, acc[6]); acc[7] = fmaf(uhi(v2.w), cf2, acc[7]);
            acc[0] = fmaf(ulo(v3.x), cf3, acc[0]); acc[1] = fmaf(uhi(v3.x), cf3, acc[1]);
            acc[2] = fmaf(ulo(v3.y), cf3, acc[2]); acc[3] = fmaf(uhi(v3.y), cf3, acc[3]);
            acc[4] = fmaf(ulo(v3.z), cf3, acc[4]); acc[5] = fmaf(uhi(v3.z), cf3, acc[5]);
            acc[6] = fmaf(ulo(v3.w), cf3, acc[6]); acc[7] = fmaf(uhi(v3.w), cf3, acc[7]);
        }
    }
#pragma unroll
    for (int i = 0; i < 8; ++i){
        acc[i] += __shfl_xor(acc[i], 16);
        acc[i] += __shfl_xor(acc[i], 32);
    }
    if (sub == 0){
        float d = rsqrtf(1.0f + (float)c0);
        float selfs = SCALESRC ? d : 1.f;
        uint4 sv = *(const uint4*)&hwu[(size_t)row * 64 + cg * 4];
        float sf[8] = {ulo(sv.x), uhi(sv.x), ulo(sv.y), uhi(sv.y),
                       ulo(sv.z), uhi(sv.z), ulo(sv.w), uhi(sv.w)};
        float4 c0v = *(const float4*)&cb[cg * 8], c1v = *(const float4*)&cb[cg * 8 + 4];
        float4 g0v = *(const float4*)&bg[cg * 8], g1v = *(const float4*)&bg[cg * 8 + 4];
        float4 b0v = *(const float4*)&bb[cg * 8], b1v = *(const float4*)&bb[cg * 8 + 4];
        float cc[8] = {c0v.x, c0v.y, c0v.z, c0v.w, c1v.x, c1v.y, c1v.z, c1v.w};
        float gg[8] = {g0v.x, g0v.y, g0v.z, g0v.w, g1v.x, g1v.y, g1v.z, g1v.w};
        float bo[8] = {b0v.x, b0v.y, b0v.z, b0v.w, b1v.x, b1v.y, b1v.z, b1v.w};
        float4 cur0 = *(const float4*)&h[(size_t)row * 128 + cg * 8];
        float4 cur1 = *(const float4*)&h[(size_t)row * 128 + cg * 8 + 4];
        float o[8] = {cur0.x, cur0.y, cur0.z, cur0.w, cur1.x, cur1.y, cur1.z, cur1.w};
#pragma unroll
        for (int i = 0; i < 8; ++i){
            float v = gg[i] * (((acc[i] + sf[i] * selfs) * d + cc[i]) * BN_S) + bo[i];
            o[i] += fmaxf(v, 0.f);
        }
        if (WRITEH){
            *(float4*)&h[(size_t)row * 128 + cg * 8] = make_float4(o[0], o[1], o[2], o[3]);
            *(float4*)&h[(size_t)row * 128 + cg * 8 + 4] = make_float4(o[4], o[5], o[6], o[7]);
        }
        uint4 pk;
        pk.x = (unsigned)f2bs(o[0]) | ((unsigned)f2bs(o[1]) << 16);
        pk.y = (unsigned)f2bs(o[2]) | ((unsigned)f2bs(o[3]) << 16);
        pk.z = (unsigned)f2bs(o[4]) | ((unsigned)f2bs(o[5]) << 16);
        pk.w = (unsigned)f2bs(o[6]) | ((unsigned)f2bs(o[7]) << 16);
        hb16o[(size_t)row * 16 + cg] = pk;
    }
}

__global__ __launch_bounds__(256) void k_agg1(
    const unsigned* __restrict__ hwu, float* __restrict__ h,
    const int* __restrict__ cnt, const unsigned short* __restrict__ slots,
    const float* __restrict__ cb, const float* __restrict__ bg, const float* __restrict__ bb,
    uint4* __restrict__ hb16o, int N)
{
    agg_body<1, 1>(hwu, h, cnt, slots, cb, bg, bb, hb16o, N);
}

__global__ __launch_bounds__(256) void k_agg(
    const unsigned* __restrict__ hwu, float* __restrict__ h,
    const int* __restrict__ cnt, const unsigned short* __restrict__ slots,
    const float* __restrict__ cb, const float* __restrict__ bg, const float* __restrict__ bb,
    uint4* __restrict__ hb16o, int N)
{
    agg_body<1, 0>(hwu, h, cnt, slots, cb, bg, bb, hb16o, N);
}

__global__ __launch_bounds__(256) void k_agg3(
    const unsigned* __restrict__ hwu, float* __restrict__ h,
    const int* __restrict__ cnt, const unsigned short* __restrict__ slots,
    const float* __restrict__ cb, const float* __restrict__ bg, const float* __restrict__ bb,
    uint4* __restrict__ hb16o, int N)
{
    agg_body<0, 0>(hwu, h, cnt, slots, cb, bg, bb, hb16o, N);
}

// ---------------- MFMA fused heads: 2D grid (y = head), bf16 gather ----------------
__global__ __launch_bounds__(256) void k_headmm(
    const uint4* __restrict__ hb16, const int* __restrict__ gidx,
    const uint4* __restrict__ p1v, const uint4* __restrict__ p2v,
    const float* __restrict__ hb1, const float* __restrict__ hg1, const float* __restrict__ hbb1,
    const float* __restrict__ hb2,
    const float* __restrict__ hW3, const float* __restrict__ hb3,
    const float* __restrict__ ob1, const float* __restrict__ og1, const float* __restrict__ obb1,
    const float* __restrict__ ob2, const float* __restrict__ og2, const float* __restrict__ obb2,
    const float* __restrict__ oW3, const float* __restrict__ ob3,
    float* __restrict__ out, int G)
{
    __shared__ __align__(16) unsigned sxg[64 * 68];
    __shared__ __align__(16) unsigned sz1u[64 * 36];
    __shared__ __align__(16) unsigned sz2u[64 * 20];
    __shared__ float sb1[64], sg1[64], sbb1[64];
    __shared__ float sb2[32], sg2[32], sbb2[32];
    __shared__ float sW3[96];
    __shared__ float sb3[3];
    __shared__ int sgi[64];

    int t = threadIdx.x;
    int gblk = blockIdx.x;
    int y = blockIdx.y;
    bool bn2 = (y == 4);
    int w = t >> 6, l = t & 63;
    int lanen = l & 15, quad = l >> 4;

    const float* b1  = bn2 ? ob1  : (hb1 + y * 64);
    const float* g1  = bn2 ? og1  : (hg1 + y * 64);
    const float* bb1 = bn2 ? obb1 : (hbb1 + y * 64);
    const float* b2  = bn2 ? ob2  : (hb2 + y * 32);
    const float* W3  = bn2 ? oW3  : (hW3 + y * 32);
    const float* b3  = bn2 ? ob3  : (hb3 + y);
    int nc3 = bn2 ? 3 : 1;

    if (t < 64){
        sb1[t] = b1[t]; sg1[t] = g1[t]; sbb1[t] = bb1[t];
        if (t < 3) sb3[t] = (t < nc3) ? b3[t] : 0.f;
    } else if (t < 96){
        int p = t - 64;
        sb2[p] = b2[p];
        sg2[p] = bn2 ? og2[p] : 1.f;
        sbb2[p] = bn2 ? obb2[p] : 0.f;
    } else if (t < 192){
        int i = t - 96;
        sW3[i] = (i < 32 * nc3) ? W3[i] : 0.f;
    } else {
        int r = t - 192;
        int g = gblk * 64 + r;
        sgi[r] = (g < G) ? gidx[g] : 0;
    }
    __syncthreads();
    for (int i = t; i < 1024; i += 256){
        int r = i >> 4, c = i & 15;
        int node = sgi[r];
        uint4 v = hb16[(size_t)node * 16 + c];
        *(uint4*)&sxg[r * 68 + c * 4] = v;
    }
    __syncthreads();

    f32x4 acc1[4] = {{0.f,0.f,0.f,0.f},{0.f,0.f,0.f,0.f},{0.f,0.f,0.f,0.f},{0.f,0.f,0.f,0.f}};
#pragma unroll
    for (int kc = 0; kc < 4; ++kc){
        U128 a;
        a.u = *(const uint4*)&sxg[(w * 16 + lanen) * 68 + kc * 16 + quad * 4];
#pragma unroll
        for (int nt = 0; nt < 4; ++nt){
            U128 bfr;
            bfr.u = p1v[((y * 4 + nt) * 4 + kc) * 64 + l];
            acc1[nt] = __builtin_amdgcn_mfma_f32_16x16x32_bf16(a.s, bfr.s, acc1[nt], 0, 0, 0);
        }
    }
    {
        unsigned short* sz1s = (unsigned short*)sz1u;
#pragma unroll
        for (int nt = 0; nt < 4; ++nt){
            int n = nt * 16 + lanen;
            float g = sg1[n], bia = sb1[n], bt = sbb1[n];
#pragma unroll
            for (int r = 0; r < 4; ++r){
                int row = w * 16 + quad * 4 + r;
                float v = g * ((acc1[nt][r] + bia) * BN_S) + bt;
                sz1s[row * 72 + n] = f2bs(fmaxf(v, 0.f));
            }
        }
    }
    __syncthreads();

    f32x4 acc2[2] = {{0.f,0.f,0.f,0.f},{0.f,0.f,0.f,0.f}};
#pragma unroll
    for (int kc = 0; kc < 2; ++kc){
        U128 a;
        a.u = *(const uint4*)&sz1u[(w * 16 + lanen) * 36 + kc * 16 + quad * 4];
#pragma unroll
        for (int nt = 0; nt < 2; ++nt){
            U128 bfr;
            bfr.u = p2v[((y * 2 + nt) * 2 + kc) * 64 + l];
            acc2[nt] = __builtin_amdgcn_mfma_f32_16x16x32_bf16(a.s, bfr.s, acc2[nt], 0, 0, 0);
        }
    }
    {
        unsigned short* sz2s = (unsigned short*)sz2u;
#pragma unroll
        for (int nt = 0; nt < 2; ++nt){
            int n = nt * 16 + lanen;
            float bia = sb2[n], g = sg2[n], bt = sbb2[n];
#pragma unroll
            for (int r = 0; r < 4; ++r){
                int row = w * 16 + quad * 4 + r;
                float v = acc2[nt][r] + bia;
                if (bn2) v = g * (v * BN_S) + bt;
                sz2s[row * 40 + n] = f2bs(fmaxf(v, 0.f));
            }
        }
    }
    __syncthreads();

    const unsigned short* sz2s = (const unsigned short*)sz2u;
    if (!bn2){
        if (t < 64){
            int g = gblk * 64 + t;
            if (g < G){
                float s = sb3[0];
#pragma unroll
                for (int p = 0; p < 32; ++p) s = fmaf(bs2f(sz2s[t * 40 + p]), sW3[p], s);
                out[(size_t)g * 7 + y] = s;
            }
        }
    } else {
        if (t < 192){
            int gl = t / 3, c = t % 3;
            int g = gblk * 64 + gl;
            if (g < G){
                float s = sb3[c];
#pragma unroll
                for (int p = 0; p < 32; ++p) s = fmaf(bs2f(sz2s[gl * 40 + p]), sW3[p * 3 + c], s);
                out[(size_t)g * 7 + 4 + c] = s;
            }
        }
    }
}

extern "C" void kernel_launch(void* const* d_in, const int* in_sizes, int n_in,
                              void* d_out, int out_size, void* d_ws, size_t ws_size,
                              hipStream_t stream)
{
    const float* x    = (const float*)d_in[0];
    const int* esrc   = (const int*)d_in[1];
    const int* edst   = (const int*)d_in[2];
    const int* gidx   = (const int*)d_in[3];
    const float* in_g = (const float*)d_in[4];
    const float* in_b = (const float*)d_in[5];
    const float* lin_W = (const float*)d_in[6];
    const float* lin_b = (const float*)d_in[7];
    const float* bn0_g = (const float*)d_in[8];
    const float* bn0_b = (const float*)d_in[9];
    const float* cW[3] = {(const float*)d_in[10], (const float*)d_in[14], (const float*)d_in[18]};
    const float* cb[3] = {(const float*)d_in[11], (const float*)d_in[15], (const float*)d_in[19]};
    const float* bg[3] = {(const float*)d_in[12], (const float*)d_in[16], (const float*)d_in[20]};
    const float* bb[3] = {(const float*)d_in[13], (const float*)d_in[17], (const float*)d_in[21]};
    const float* hW1 = (const float*)d_in[22];
    const float* hb1 = (const float*)d_in[23];
    const float* hg1 = (const float*)d_in[24];
    const float* hbb1 = (const float*)d_in[25];
    const float* hW2 = (const float*)d_in[26];
    const float* hb2 = (const float*)d_in[27];
    const float* hW3 = (const float*)d_in[28];
    const float* hb3 = (const float*)d_in[29];
    const float* oW1 = (const float*)d_in[30];
    const float* ob1 = (const float*)d_in[31];
    const float* og1 = (const float*)d_in[32];
    const float* obb1 = (const float*)d_in[33];
    const float* oW2 = (const float*)d_in[34];
    const float* ob2 = (const float*)d_in[35];
    const float* og2 = (const float*)d_in[36];
    const float* obb2 = (const float*)d_in[37];
    const float* oW3 = (const float*)d_in[38];
    const float* ob3 = (const float*)d_in[39];

    const int N = in_sizes[0] / HDIM;
    const int E = in_sizes[1];
    const int G = in_sizes[3];

    char* wsp = (char*)d_ws;
    size_t off = 0;
    auto alloc = [&](size_t bytes) -> char* {
        char* p = wsp + off;
        off = (off + bytes + 255) & ~(size_t)255;
        return p;
    };
    int* cnt      = (int*)alloc((size_t)N * 4);
    unsigned short* slots = (unsigned short*)alloc((size_t)N * PAD * 2);
    float* hbuf   = (float*)alloc((size_t)N * HDIM * 4);
    unsigned short* hwbA = (unsigned short*)alloc((size_t)N * HDIM * 2);
    unsigned short* hwbB = (unsigned short*)alloc((size_t)N * HDIM * 2);
    unsigned short* hb16 = (unsigned short*)alloc((size_t)N * HDIM * 2);
    unsigned short* p1 = (unsigned short*)alloc(40960 * 2);
    unsigned short* p2 = (unsigned short*)alloc(10240 * 2);
    unsigned short* wf = (unsigned short*)alloc((size_t)4 * 32768 * 2);

    int gb = (N + 63) / 64;
    int nCB = (E + 255) / 256;
    int prepTot = 65536 + 51200 + N;

    // 1: prepack weights + zero cnt (memset folded in)
    k_prep<<<dim3((prepTot + 255) / 256), dim3(256), 0, stream>>>(
        lin_W, cW[0], cW[1], cW[2], hW1, oW1, hW2, oW2, wf, p1, p2, cnt, N);
    // 2: fused count (first) + gemm0+gemm1 (UNSCALED hwbA); fully independent halves
    k_cg01e<<<dim3(nCB + gb), dim3(256), 0, stream>>>(
        x, (const uint4*)wf, (const uint4*)(wf + (size_t)32768),
        in_g, in_b, lin_b, bn0_g, bn0_b, hbuf, hwbA, N, nCB,
        esrc, edst, cnt, slots, E);
    // 3: agg layer-1 (scales gathered rows by dis[src] from cnt) -> h1 (fp32 + bf16)
    k_agg1<<<dim3((N + 3) / 4), dim3(256), 0, stream>>>(
        (const unsigned*)hwbA, hbuf, cnt, slots, cb[0], bg[0], bb[0], (uint4*)hb16, N);
    // 4: gemm layer-2 (dis-prescaled; cnt ready)
    k_gemmb<<<dim3(gb), dim3(256), 0, stream>>>(
        (const uint4*)hb16, (const uint4*)(wf + (size_t)2 * 32768), cnt, hwbB, N);
    // 5: agg layer-2 -> h2
    k_agg<<<dim3((N + 3) / 4), dim3(256), 0, stream>>>(
        (const unsigned*)hwbB, hbuf, cnt, slots, cb[1], bg[1], bb[1], (uint4*)hb16, N);
    // 6: gemm layer-3
    k_gemmb<<<dim3(gb), dim3(256), 0, stream>>>(
        (const uint4*)hb16, (const uint4*)(wf + (size_t)3 * 32768), cnt, hwbA, N);
    // 7: agg layer-3 -> bf16 h3 only
    k_agg3<<<dim3((N + 3) / 4), dim3(256), 0, stream>>>(
        (const unsigned*)hwbA, hbuf, cnt, slots, cb[2], bg[2], bb[2], (uint4*)hb16, N);
    // 8: heads — 2D grid, 5 heads x 256 game-blocks
    k_headmm<<<dim3((G + 63) / 64, 5), dim3(256), 0, stream>>>(
        (const uint4*)hb16, gidx, (const uint4*)p1, (const uint4*)p2,
        hb1, hg1, hbb1, hb2, hW3, hb3,
        ob1, og1, obb1, ob2, og2, obb2, oW3, ob3,
        (float*)d_out, G);
}

// Round 10
// 322.537 us; speedup vs baseline: 1.3788x; 1.0169x over previous
//
#include <hip/hip_runtime.h>
#include <hip/hip_bf16.h>

#define HDIM 128
#define PAD 64
static constexpr float BN_S = 0.99999500003749968751f; // 1/sqrt(1+1e-5)

typedef float f32x4 __attribute__((ext_vector_type(4)));
typedef short s16x8 __attribute__((ext_vector_type(8)));

union U128 { uint4 u; s16x8 s; };

__device__ __forceinline__ unsigned short f2bs(float f){
    union{float f; unsigned u;} c; c.f = f;
    unsigned r = c.u + 0x7fffu + ((c.u >> 16) & 1u);
    return (unsigned short)(r >> 16);
}
__device__ __forceinline__ float bs2f(unsigned short s){
    union{unsigned u; float f;} c; c.u = ((unsigned)s) << 16;
    return c.f;
}
__device__ __forceinline__ float ulo(unsigned u){ union{unsigned i; float f;} c; c.i = u << 16; return c.f; }
__device__ __forceinline__ float uhi(unsigned u){ union{unsigned i; float f;} c; c.i = u & 0xffff0000u; return c.f; }

// ---------------- prepack all weights + zero cnt (memset folded in) ----------------
__global__ __launch_bounds__(256) void k_prep(
    const float* __restrict__ linW, const float* __restrict__ cW1,
    const float* __restrict__ cW2, const float* __restrict__ cW3,
    const float* __restrict__ hW1, const float* __restrict__ oW1,
    const float* __restrict__ hW2, const float* __restrict__ oW2,
    unsigned short* __restrict__ wf, unsigned short* __restrict__ p1,
    unsigned short* __restrict__ p2, int* __restrict__ cnt, int N)
{
    int id = blockIdx.x * 256 + threadIdx.x;
    if (id < 65536){
        int mat = id >> 14;
        int el = id & 16383;
        int k = el >> 7, n = el & 127;
        const float* W = (mat == 0) ? linW : (mat == 1) ? cW1 : (mat == 2) ? cW2 : cW3;
        float v = W[k * 128 + n];
        unsigned short hs = f2bs(v);
        unsigned short ls = f2bs(v - bs2f(hs));
        int nt = n >> 4, lanen = n & 15, kc = k >> 5, quad = (k >> 3) & 3, j = k & 7;
        int lane = quad * 16 + lanen;
        size_t base = (size_t)mat * 32768;
        wf[base + (size_t)(((nt * 4 + kc) * 2 + 0) * 64 + lane) * 8 + j] = hs;
        wf[base + (size_t)(((nt * 4 + kc) * 2 + 1) * 64 + lane) * 8 + j] = ls;
    } else if (id < 65536 + 51200){
        int id1 = id - 65536;
        if (id1 < 40960){
            int j = id1 & 7, lane = (id1 >> 3) & 63, kc = (id1 >> 9) & 3, nt = (id1 >> 11) & 3, y = id1 >> 13;
            int k = kc * 32 + (lane >> 4) * 8 + j;
            int n = nt * 16 + (lane & 15);
            float w = (y < 4) ? hW1[(y * 128 + k) * 64 + n] : oW1[k * 64 + n];
            p1[id1] = f2bs(w);
        } else {
            int id2 = id1 - 40960;
            int j = id2 & 7, lane = (id2 >> 3) & 63, kc = (id2 >> 9) & 1, nt = (id2 >> 10) & 1, y = id2 >> 11;
            int k = kc * 32 + (lane >> 4) * 8 + j;
            int n = nt * 16 + (lane & 15);
            float w = (y < 4) ? hW2[(y * 64 + k) * 32 + n] : oW2[k * 32 + n];
            p2[id2] = f2bs(w);
        }
    } else {
        int z = id - (65536 + 51200);
        if (z < N) cnt[z] = 0;
    }
}

// ---------------- fused: gemm0+gemm1 blocks (FIRST) + independent edge count blocks ----------------
// bid < gb:  gemm tile. gemm0 (split-A) -> fp32 h; gemm1 (bf16) -> UNSCALED bf16 hwout.
//            No dependence on cnt/slots.
// bid >= gb: count blocks trailing (r7-proven ordering: they fill scheduling gaps around
//            the resident gemm blocks), 1 edge/thread: rank = atomicAdd(cnt[dst]);
//            slots16[dst*PAD+rank] = (ushort)src. No inter-block waiting (round-6 lesson).
__global__ __launch_bounds__(256) void k_cg01e(
    const float* __restrict__ x, const uint4* __restrict__ wf0, const uint4* __restrict__ wf1,
    const float* __restrict__ ing, const float* __restrict__ inb,
    const float* __restrict__ lb, const float* __restrict__ g0, const float* __restrict__ b0,
    float* __restrict__ hout, unsigned short* __restrict__ hwout, int nrows, int gb,
    const int* __restrict__ esrc, const int* __restrict__ edst,
    int* __restrict__ cnt, unsigned short* __restrict__ slots, int E)
{
    __shared__ __align__(16) unsigned sbuf[64 * 136];
    int bid = blockIdx.x;
    int t = threadIdx.x;

    if (bid >= gb){
        int e = (bid - gb) * 256 + t;
        if (e < E){
            int d = edst[e];
            int r = atomicAdd(&cnt[d], 1);
            if (r < PAD) slots[(size_t)d * PAD + r] = (unsigned short)esrc[e];  // N < 65536
        }
        return;
    }

    unsigned* sAhi = sbuf;
    unsigned* sAlo = sbuf + 64 * 68;
    int row0 = bid * 64;
    for (int i = t; i < 2048; i += 256){
        int r = i >> 5, q = i & 31;
        int gr = row0 + r;
        float4 v = make_float4(0.f, 0.f, 0.f, 0.f);
        if (gr < nrows) v = *(const float4*)&x[(size_t)gr * 128 + q * 4];
        float4 g = *(const float4*)&ing[q * 4];
        float4 bo = *(const float4*)&inb[q * 4];
        v.x = v.x * (g.x * BN_S) + bo.x;
        v.y = v.y * (g.y * BN_S) + bo.y;
        v.z = v.z * (g.z * BN_S) + bo.z;
        v.w = v.w * (g.w * BN_S) + bo.w;
        unsigned u0 = __float_as_uint(v.x), u1 = __float_as_uint(v.y);
        unsigned u2 = __float_as_uint(v.z), u3 = __float_as_uint(v.w);
        uint2 hi = make_uint2((u0 >> 16) | (u1 & 0xffff0000u), (u2 >> 16) | (u3 & 0xffff0000u));
        unsigned short l0 = f2bs(v.x - __uint_as_float(u0 & 0xffff0000u));
        unsigned short l1 = f2bs(v.y - __uint_as_float(u1 & 0xffff0000u));
        unsigned short l2 = f2bs(v.z - __uint_as_float(u2 & 0xffff0000u));
        unsigned short l3 = f2bs(v.w - __uint_as_float(u3 & 0xffff0000u));
        uint2 lo = make_uint2((unsigned)l0 | ((unsigned)l1 << 16), (unsigned)l2 | ((unsigned)l3 << 16));
        *(uint2*)&sAhi[r * 68 + q * 2] = hi;
        *(uint2*)&sAlo[r * 68 + q * 2] = lo;
    }
    __syncthreads();

    int w = t >> 6, l = t & 63;
    int lanen = l & 15, quad = l >> 4;
    int mrow = w * 16 + lanen;
    f32x4 acc[8];
#pragma unroll
    for (int i = 0; i < 8; ++i) acc[i] = (f32x4){0.f, 0.f, 0.f, 0.f};

#pragma unroll 1
    for (int kc = 0; kc < 4; ++kc){
        U128 ahi, alo;
        ahi.u = *(const uint4*)&sAhi[mrow * 68 + kc * 16 + quad * 4];
        alo.u = *(const uint4*)&sAlo[mrow * 68 + kc * 16 + quad * 4];
        U128 whi[8];
#pragma unroll
        for (int nt = 0; nt < 8; ++nt)
            whi[nt].u = wf0[((nt * 4 + kc) * 2 + 0) * 64 + l];
#pragma unroll
        for (int nt = 0; nt < 8; ++nt)
            acc[nt] = __builtin_amdgcn_mfma_f32_16x16x32_bf16(ahi.s, whi[nt].s, acc[nt], 0, 0, 0);
#pragma unroll
        for (int nt = 0; nt < 8; ++nt)
            acc[nt] = __builtin_amdgcn_mfma_f32_16x16x32_bf16(alo.s, whi[nt].s, acc[nt], 0, 0, 0);
    }

    // epilogue gemm0: h tile -> LDS (f32, stride 132), coalesced fp32 global write
    __syncthreads();
    float* so = (float*)sbuf;
#pragma unroll
    for (int nt = 0; nt < 8; ++nt){
        int n = nt * 16 + lanen;
        float bias = lb[n], g = g0[n], bo = b0[n];
#pragma unroll
        for (int r = 0; r < 4; ++r){
            int row = w * 16 + quad * 4 + r;
            float v = g * ((acc[nt][r] + bias) * BN_S) + bo;
            so[row * 132 + n] = fmaxf(v, 0.f);
        }
    }
    __syncthreads();
    for (int i = t; i < 2048; i += 256){
        int row = i >> 5, c4 = (i & 31) * 4;
        int grow = row0 + row;
        if (grow < nrows)
            *(float4*)&hout[(size_t)grow * 128 + c4] = *(float4*)&so[row * 132 + c4];
    }

    // gemm1: fragments straight from so (h tile); UNSCALED bf16 out
    f32x4 acc2[8];
#pragma unroll
    for (int i = 0; i < 8; ++i) acc2[i] = (f32x4){0.f, 0.f, 0.f, 0.f};
#pragma unroll 1
    for (int kc = 0; kc < 4; ++kc){
        float4 a0 = *(const float4*)&so[mrow * 132 + kc * 32 + quad * 8];
        float4 a1 = *(const float4*)&so[mrow * 132 + kc * 32 + quad * 8 + 4];
        U128 af;
        af.u.x = (unsigned)f2bs(a0.x) | ((unsigned)f2bs(a0.y) << 16);
        af.u.y = (unsigned)f2bs(a0.z) | ((unsigned)f2bs(a0.w) << 16);
        af.u.z = (unsigned)f2bs(a1.x) | ((unsigned)f2bs(a1.y) << 16);
        af.u.w = (unsigned)f2bs(a1.z) | ((unsigned)f2bs(a1.w) << 16);
        U128 wh[8];
#pragma unroll
        for (int nt = 0; nt < 8; ++nt)
            wh[nt].u = wf1[((nt * 4 + kc) * 2 + 0) * 64 + l];
#pragma unroll
        for (int nt = 0; nt < 8; ++nt)
            acc2[nt] = __builtin_amdgcn_mfma_f32_16x16x32_bf16(af.s, wh[nt].s, acc2[nt], 0, 0, 0);
    }
    __syncthreads();   // all waves done reading so
    unsigned short* ss = (unsigned short*)sbuf;
#pragma unroll
    for (int nt = 0; nt < 8; ++nt){
        int n = nt * 16 + lanen;
#pragma unroll
        for (int r = 0; r < 4; ++r){
            int row = w * 16 + quad * 4 + r;
            ss[row * 136 + n] = f2bs(acc2[nt][r]);
        }
    }
    __syncthreads();
    for (int i = t; i < 1024; i += 256){
        int row = i >> 4, c = i & 15;
        int grow = row0 + row;
        if (grow < nrows)
            *(uint4*)&hwout[(size_t)grow * 128 + c * 8] = *(uint4*)&ss[row * 136 + c * 8];
    }
}

// ---------------- standalone layer gemm: bf16 h in, dis-prescaled bf16 out ----------------
__global__ __launch_bounds__(256) void k_gemmb(
    const uint4* __restrict__ hb16, const uint4* __restrict__ wf,
    const int* __restrict__ cnt,
    unsigned short* __restrict__ hwout, int nrows)
{
    __shared__ __align__(16) unsigned sbuf[64 * 68];
    __shared__ float sdis[64];
    int t = threadIdx.x;
    int row0 = blockIdx.x * 64;
    if (t < 64){
        int gr = row0 + t;
        sdis[t] = (gr < nrows) ? rsqrtf(1.0f + (float)cnt[gr]) : 1.0f;
    }
    for (int i = t; i < 1024; i += 256){
        int r = i >> 4, c = i & 15;
        int gr = row0 + r;
        uint4 v = make_uint4(0u, 0u, 0u, 0u);
        if (gr < nrows) v = hb16[(size_t)gr * 16 + c];
        *(uint4*)&sbuf[r * 68 + c * 4] = v;
    }
    __syncthreads();

    int w = t >> 6, l = t & 63;
    int lanen = l & 15, quad = l >> 4;
    int mrow = w * 16 + lanen;
    f32x4 acc[8];
#pragma unroll
    for (int i = 0; i < 8; ++i) acc[i] = (f32x4){0.f, 0.f, 0.f, 0.f};
#pragma unroll 1
    for (int kc = 0; kc < 4; ++kc){
        U128 ah;
        ah.u = *(const uint4*)&sbuf[mrow * 68 + kc * 16 + quad * 4];
        U128 wh[8];
#pragma unroll
        for (int nt = 0; nt < 8; ++nt)
            wh[nt].u = wf[((nt * 4 + kc) * 2 + 0) * 64 + l];
#pragma unroll
        for (int nt = 0; nt < 8; ++nt)
            acc[nt] = __builtin_amdgcn_mfma_f32_16x16x32_bf16(ah.s, wh[nt].s, acc[nt], 0, 0, 0);
    }
    __syncthreads();
    unsigned short* ss = (unsigned short*)sbuf;
#pragma unroll
    for (int nt = 0; nt < 8; ++nt){
        int n = nt * 16 + lanen;
#pragma unroll
        for (int r = 0; r < 4; ++r){
            int row = w * 16 + quad * 4 + r;
            ss[row * 136 + n] = f2bs(acc[nt][r] * sdis[row]);
        }
    }
    __syncthreads();
    for (int i = t; i < 1024; i += 256){
        int row = i >> 4, c = i & 15;
        int grow = row0 + row;
        if (grow < nrows)
            *(uint4*)&hwout[(size_t)grow * 128 + c * 8] = *(uint4*)&ss[row * 136 + c * 8];
    }
}

// ---------------- padded-slot aggregate (full-row; r7 proven form) ----------------
// SCALESRC=1 (layer 1): hwu rows UNSCALED, per-edge coef = dis[src]; self term *dis[row].
// WRITEH=1: write fp32 h (residual) + bf16 h; WRITEH=0 (final layer): bf16 h only.
template<int WRITEH, int SCALESRC>
__device__ __forceinline__ void agg_body(
    const unsigned* __restrict__ hwu, float* __restrict__ h,
    const int* __restrict__ cnt, const unsigned short* __restrict__ slots,
    const float* __restrict__ cb, const float* __restrict__ bg, const float* __restrict__ bb,
    uint4* __restrict__ hb16o, int N)
{
    int row = blockIdx.x * 4 + (threadIdx.x >> 6);
    if (row >= N) return;
    int l = threadIdx.x & 63;
    int sub = l >> 4, cg = l & 15;
    int c0 = cnt[row];
    int c = (c0 > PAD) ? PAD : c0;
    float acc[8];
#pragma unroll
    for (int i = 0; i < 8; ++i) acc[i] = 0.f;
    for (int p = 0; p < c; p += 16){
        int base = p + sub * 4;
        if (base < c){
            uint2 s2 = *(const uint2*)&slots[(size_t)row * PAD + base];
            int s0 = (int)(s2.x & 0xffffu);
            int t1 = (int)(s2.x >> 16);
            int t2 = (int)(s2.y & 0xffffu);
            int t3 = (int)(s2.y >> 16);
            int i1 = (base + 1 < c) ? t1 : s0;
            int i2 = (base + 2 < c) ? t2 : s0;
            int i3 = (base + 3 < c) ? t3 : s0;
            float cf0, cf1, cf2, cf3;
            if (SCALESRC){
                cf0 = rsqrtf(1.0f + (float)cnt[s0]);
                cf1 = (base + 1 < c) ? rsqrtf(1.0f + (float)cnt[i1]) : 0.f;
                cf2 = (base + 2 < c) ? rsqrtf(1.0f + (float)cnt[i2]) : 0.f;
                cf3 = (base + 3 < c) ? rsqrtf(1.0f + (float)cnt[i3]) : 0.f;
            } else {
                cf0 = 1.f;
                cf1 = (base + 1 < c) ? 1.f : 0.f;
                cf2 = (base + 2 < c) ? 1.f : 0.f;
                cf3 = (base + 3 < c) ? 1.f : 0.f;
            }
            uint4 v0 = *(const uint4*)&hwu[(size_t)s0 * 64 + cg * 4];
            uint4 v1 = *(const uint4*)&hwu[(size_t)i1 * 64 + cg * 4];
            uint4 v2 = *(const uint4*)&hwu[(size_t)i2 * 64 + cg * 4];
            uint4 v3 = *(const uint4*)&hwu[(size_t)i3 * 64 + cg * 4];
            acc[0] = fmaf(ulo(v0.x), cf0, acc[0]); acc[1] = fmaf(uhi(v0.x), cf0, acc[1]);
            acc[2] = fmaf(ulo(v0.y), cf0, acc[2]); acc[3] = fmaf(uhi(v0.y), cf0, acc[3]);
            acc[4] = fmaf(ulo(v0.z), cf0, acc[4]); acc[5] = fmaf(uhi(v0.z), cf0, acc[5]);
            acc[6] = fmaf(ulo(v0.w), cf0, acc[6]); acc[7] = fmaf(uhi(v0.w), cf0, acc[7]);
            acc[0] = fmaf(ulo(v1.x), cf1, acc[0]); acc[1] = fmaf(uhi(v1.x), cf1, acc[1]);
            acc[2] = fmaf(ulo(v1.y), cf1, acc[2]); acc[3] = fmaf(uhi(v1.y), cf1, acc[3]);
            acc[4] = fmaf(ulo(v1.z), cf1, acc[4]); acc[5] = fmaf(uhi(v1.z), cf1, acc[5]);
            acc[6] = fmaf(ulo(v1.w), cf1, acc[6]); acc[7] = fmaf(uhi(v1.w), cf1, acc[7]);
            acc[0] = fmaf(ulo(v2.x), cf2, acc[0]); acc[1] = fmaf(uhi(v2.x), cf2, acc[1]);
            acc[2] = fmaf(ulo(v2.y), cf2, acc[2]); acc[3] = fmaf(uhi(v2.y), cf2, acc[3]);
            acc[4] = fmaf(ulo(v2.z), cf2, acc[4]); acc[5] = fmaf(uhi(v2.z), cf2, acc[5]);
            acc[6] = fmaf(ulo(v2.w), cf2, acc[6]); acc[7] = fmaf(uhi(v2.w), cf2, acc[7]);
            acc[0] = fmaf(ulo(v3.x), cf3, acc[0]); acc[1] = fmaf(uhi(v3.x), cf3, acc[1]);
            acc[2] = fmaf(ulo(v3.y), cf3, acc[2]); acc[3] = fmaf(uhi(v3.y), cf3, acc[3]);
            acc[4] = fmaf(ulo(v3.z), cf3, acc[4]); acc[5] = fmaf(uhi(v3.z), cf3, acc[5]);
            acc[6] = fmaf(ulo(v3.w), cf3, acc[6]); acc[7] = fmaf(uhi(v3.w), cf3, acc[7]);
        }
    }
#pragma unroll
    for (int i = 0; i < 8; ++i){
        acc[i] += __shfl_xor(acc[i], 16);
        acc[i] += __shfl_xor(acc[i], 32);
    }
    if (sub == 0){
        float d = rsqrtf(1.0f + (float)c0);
        float selfs = SCALESRC ? d : 1.f;
        uint4 sv = *(const uint4*)&hwu[(size_t)row * 64 + cg * 4];
        float sf[8] = {ulo(sv.x), uhi(sv.x), ulo(sv.y), uhi(sv.y),
                       ulo(sv.z), uhi(sv.z), ulo(sv.w), uhi(sv.w)};
        float4 c0v = *(const float4*)&cb[cg * 8], c1v = *(const float4*)&cb[cg * 8 + 4];
        float4 g0v = *(const float4*)&bg[cg * 8], g1v = *(const float4*)&bg[cg * 8 + 4];
        float4 b0v = *(const float4*)&bb[cg * 8], b1v = *(const float4*)&bb[cg * 8 + 4];
        float cc[8] = {c0v.x, c0v.y, c0v.z, c0v.w, c1v.x, c1v.y, c1v.z, c1v.w};
        float gg[8] = {g0v.x, g0v.y, g0v.z, g0v.w, g1v.x, g1v.y, g1v.z, g1v.w};
        float bo[8] = {b0v.x, b0v.y, b0v.z, b0v.w, b1v.x, b1v.y, b1v.z, b1v.w};
        float4 cur0 = *(const float4*)&h[(size_t)row * 128 + cg * 8];
        float4 cur1 = *(const float4*)&h[(size_t)row * 128 + cg * 8 + 4];
        float o[8] = {cur0.x, cur0.y, cur0.z, cur0.w, cur1.x, cur1.y, cur1.z, cur1.w};
#pragma unroll
        for (int i = 0; i < 8; ++i){
            float v = gg[i] * (((acc[i] + sf[i] * selfs) * d + cc[i]) * BN_S) + bo[i];
            o[i] += fmaxf(v, 0.f);
        }
        if (WRITEH){
            *(float4*)&h[(size_t)row * 128 + cg * 8] = make_float4(o[0], o[1], o[2], o[3]);
            *(float4*)&h[(size_t)row * 128 + cg * 8 + 4] = make_float4(o[4], o[5], o[6], o[7]);
        }
        uint4 pk;
        pk.x = (unsigned)f2bs(o[0]) | ((unsigned)f2bs(o[1]) << 16);
        pk.y = (unsigned)f2bs(o[2]) | ((unsigned)f2bs(o[3]) << 16);
        pk.z = (unsigned)f2bs(o[4]) | ((unsigned)f2bs(o[5]) << 16);
        pk.w = (unsigned)f2bs(o[6]) | ((unsigned)f2bs(o[7]) << 16);
        hb16o[(size_t)row * 16 + cg] = pk;
    }
}

__global__ __launch_bounds__(256) void k_agg1(
    const unsigned* __restrict__ hwu, float* __restrict__ h,
    const int* __restrict__ cnt, const unsigned short* __restrict__ slots,
    const float* __restrict__ cb, const float* __restrict__ bg, const float* __restrict__ bb,
    uint4* __restrict__ hb16o, int N)
{
    agg_body<1, 1>(hwu, h, cnt, slots, cb, bg, bb, hb16o, N);
}

__global__ __launch_bounds__(256) void k_agg(
    const unsigned* __restrict__ hwu, float* __restrict__ h,
    const int* __restrict__ cnt, const unsigned short* __restrict__ slots,
    const float* __restrict__ cb, const float* __restrict__ bg, const float* __restrict__ bb,
    uint4* __restrict__ hb16o, int N)
{
    agg_body<1, 0>(hwu, h, cnt, slots, cb, bg, bb, hb16o, N);
}

__global__ __launch_bounds__(256) void k_agg3(
    const unsigned* __restrict__ hwu, float* __restrict__ h,
    const int* __restrict__ cnt, const unsigned short* __restrict__ slots,
    const float* __restrict__ cb, const float* __restrict__ bg, const float* __restrict__ bb,
    uint4* __restrict__ hb16o, int N)
{
    agg_body<0, 0>(hwu, h, cnt, slots, cb, bg, bb, hb16o, N);
}

// ---------------- MFMA fused heads: 2D grid (y = head), bf16 gather ----------------
__global__ __launch_bounds__(256) void k_headmm(
    const uint4* __restrict__ hb16, const int* __restrict__ gidx,
    const uint4* __restrict__ p1v, const uint4* __restrict__ p2v,
    const float* __restrict__ hb1, const float* __restrict__ hg1, const float* __restrict__ hbb1,
    const float* __restrict__ hb2,
    const float* __restrict__ hW3, const float* __restrict__ hb3,
    const float* __restrict__ ob1, const float* __restrict__ og1, const float* __restrict__ obb1,
    const float* __restrict__ ob2, const float* __restrict__ og2, const float* __restrict__ obb2,
    const float* __restrict__ oW3, const float* __restrict__ ob3,
    float* __restrict__ out, int G)
{
    __shared__ __align__(16) unsigned sxg[64 * 68];
    __shared__ __align__(16) unsigned sz1u[64 * 36];
    __shared__ __align__(16) unsigned sz2u[64 * 20];
    __shared__ float sb1[64], sg1[64], sbb1[64];
    __shared__ float sb2[32], sg2[32], sbb2[32];
    __shared__ float sW3[96];
    __shared__ float sb3[3];
    __shared__ int sgi[64];

    int t = threadIdx.x;
    int gblk = blockIdx.x;
    int y = blockIdx.y;
    bool bn2 = (y == 4);
    int w = t >> 6, l = t & 63;
    int lanen = l & 15, quad = l >> 4;

    const float* b1  = bn2 ? ob1  : (hb1 + y * 64);
    const float* g1  = bn2 ? og1  : (hg1 + y * 64);
    const float* bb1 = bn2 ? obb1 : (hbb1 + y * 64);
    const float* b2  = bn2 ? ob2  : (hb2 + y * 32);
    const float* W3  = bn2 ? oW3  : (hW3 + y * 32);
    const float* b3  = bn2 ? ob3  : (hb3 + y);
    int nc3 = bn2 ? 3 : 1;

    if (t < 64){
        sb1[t] = b1[t]; sg1[t] = g1[t]; sbb1[t] = bb1[t];
        if (t < 3) sb3[t] = (t < nc3) ? b3[t] : 0.f;
    } else if (t < 96){
        int p = t - 64;
        sb2[p] = b2[p];
        sg2[p] = bn2 ? og2[p] : 1.f;
        sbb2[p] = bn2 ? obb2[p] : 0.f;
    } else if (t < 192){
        int i = t - 96;
        sW3[i] = (i < 32 * nc3) ? W3[i] : 0.f;
    } else {
        int r = t - 192;
        int g = gblk * 64 + r;
        sgi[r] = (g < G) ? gidx[g] : 0;
    }
    __syncthreads();
    for (int i = t; i < 1024; i += 256){
        int r = i >> 4, c = i & 15;
        int node = sgi[r];
        uint4 v = hb16[(size_t)node * 16 + c];
        *(uint4*)&sxg[r * 68 + c * 4] = v;
    }
    __syncthreads();

    f32x4 acc1[4] = {{0.f,0.f,0.f,0.f},{0.f,0.f,0.f,0.f},{0.f,0.f,0.f,0.f},{0.f,0.f,0.f,0.f}};
#pragma unroll
    for (int kc = 0; kc < 4; ++kc){
        U128 a;
        a.u = *(const uint4*)&sxg[(w * 16 + lanen) * 68 + kc * 16 + quad * 4];
#pragma unroll
        for (int nt = 0; nt < 4; ++nt){
            U128 bfr;
            bfr.u = p1v[((y * 4 + nt) * 4 + kc) * 64 + l];
            acc1[nt] = __builtin_amdgcn_mfma_f32_16x16x32_bf16(a.s, bfr.s, acc1[nt], 0, 0, 0);
        }
    }
    {
        unsigned short* sz1s = (unsigned short*)sz1u;
#pragma unroll
        for (int nt = 0; nt < 4; ++nt){
            int n = nt * 16 + lanen;
            float g = sg1[n], bia = sb1[n], bt = sbb1[n];
#pragma unroll
            for (int r = 0; r < 4; ++r){
                int row = w * 16 + quad * 4 + r;
                float v = g * ((acc1[nt][r] + bia) * BN_S) + bt;
                sz1s[row * 72 + n] = f2bs(fmaxf(v, 0.f));
            }
        }
    }
    __syncthreads();

    f32x4 acc2[2] = {{0.f,0.f,0.f,0.f},{0.f,0.f,0.f,0.f}};
#pragma unroll
    for (int kc = 0; kc < 2; ++kc){
        U128 a;
        a.u = *(const uint4*)&sz1u[(w * 16 + lanen) * 36 + kc * 16 + quad * 4];
#pragma unroll
        for (int nt = 0; nt < 2; ++nt){
            U128 bfr;
            bfr.u = p2v[((y * 2 + nt) * 2 + kc) * 64 + l];
            acc2[nt] = __builtin_amdgcn_mfma_f32_16x16x32_bf16(a.s, bfr.s, acc2[nt], 0, 0, 0);
        }
    }
    {
        unsigned short* sz2s = (unsigned short*)sz2u;
#pragma unroll
        for (int nt = 0; nt < 2; ++nt){
            int n = nt * 16 + lanen;
            float bia = sb2[n], g = sg2[n], bt = sbb2[n];
#pragma unroll
            for (int r = 0; r < 4; ++r){
                int row = w * 16 + quad * 4 + r;
                float v = acc2[nt][r] + bia;
                if (bn2) v = g * (v * BN_S) + bt;
                sz2s[row * 40 + n] = f2bs(fmaxf(v, 0.f));
            }
        }
    }
    __syncthreads();

    const unsigned short* sz2s = (const unsigned short*)sz2u;
    if (!bn2){
        if (t < 64){
            int g = gblk * 64 + t;
            if (g < G){
                float s = sb3[0];
#pragma unroll
                for (int p = 0; p < 32; ++p) s = fmaf(bs2f(sz2s[t * 40 + p]), sW3[p], s);
                out[(size_t)g * 7 + y] = s;
            }
        }
    } else {
        if (t < 192){
            int gl = t / 3, c = t % 3;
            int g = gblk * 64 + gl;
            if (g < G){
                float s = sb3[c];
#pragma unroll
                for (int p = 0; p < 32; ++p) s = fmaf(bs2f(sz2s[gl * 40 + p]), sW3[p * 3 + c], s);
                out[(size_t)g * 7 + 4 + c] = s;
            }
        }
    }
}

extern "C" void kernel_launch(void* const* d_in, const int* in_sizes, int n_in,
                              void* d_out, int out_size, void* d_ws, size_t ws_size,
                              hipStream_t stream)
{
    const float* x    = (const float*)d_in[0];
    const int* esrc   = (const int*)d_in[1];
    const int* edst   = (const int*)d_in[2];
    const int* gidx   = (const int*)d_in[3];
    const float* in_g = (const float*)d_in[4];
    const float* in_b = (const float*)d_in[5];
    const float* lin_W = (const float*)d_in[6];
    const float* lin_b = (const float*)d_in[7];
    const float* bn0_g = (const float*)d_in[8];
    const float* bn0_b = (const float*)d_in[9];
    const float* cW[3] = {(const float*)d_in[10], (const float*)d_in[14], (const float*)d_in[18]};
    const float* cb[3] = {(const float*)d_in[11], (const float*)d_in[15], (const float*)d_in[19]};
    const float* bg[3] = {(const float*)d_in[12], (const float*)d_in[16], (const float*)d_in[20]};
    const float* bb[3] = {(const float*)d_in[13], (const float*)d_in[17], (const float*)d_in[21]};
    const float* hW1 = (const float*)d_in[22];
    const float* hb1 = (const float*)d_in[23];
    const float* hg1 = (const float*)d_in[24];
    const float* hbb1 = (const float*)d_in[25];
    const float* hW2 = (const float*)d_in[26];
    const float* hb2 = (const float*)d_in[27];
    const float* hW3 = (const float*)d_in[28];
    const float* hb3 = (const float*)d_in[29];
    const float* oW1 = (const float*)d_in[30];
    const float* ob1 = (const float*)d_in[31];
    const float* og1 = (const float*)d_in[32];
    const float* obb1 = (const float*)d_in[33];
    const float* oW2 = (const float*)d_in[34];
    const float* ob2 = (const float*)d_in[35];
    const float* og2 = (const float*)d_in[36];
    const float* obb2 = (const float*)d_in[37];
    const float* oW3 = (const float*)d_in[38];
    const float* ob3 = (const float*)d_in[39];

    const int N = in_sizes[0] / HDIM;
    const int E = in_sizes[1];
    const int G = in_sizes[3];

    char* wsp = (char*)d_ws;
    size_t off = 0;
    auto alloc = [&](size_t bytes) -> char* {
        char* p = wsp + off;
        off = (off + bytes + 255) & ~(size_t)255;
        return p;
    };
    int* cnt      = (int*)alloc((size_t)N * 4);
    unsigned short* slots = (unsigned short*)alloc((size_t)N * PAD * 2);
    float* hbuf   = (float*)alloc((size_t)N * HDIM * 4);
    unsigned short* hwbA = (unsigned short*)alloc((size_t)N * HDIM * 2);
    unsigned short* hwbB = (unsigned short*)alloc((size_t)N * HDIM * 2);
    unsigned short* hb16 = (unsigned short*)alloc((size_t)N * HDIM * 2);
    unsigned short* p1 = (unsigned short*)alloc(40960 * 2);
    unsigned short* p2 = (unsigned short*)alloc(10240 * 2);
    unsigned short* wf = (unsigned short*)alloc((size_t)4 * 32768 * 2);

    int gb = (N + 63) / 64;
    int nCB = (E + 255) / 256;
    int prepTot = 65536 + 51200 + N;

    // 1: prepack weights + zero cnt (memset folded in)
    k_prep<<<dim3((prepTot + 255) / 256), dim3(256), 0, stream>>>(
        lin_W, cW[0], cW[1], cW[2], hW1, oW1, hW2, oW2, wf, p1, p2, cnt, N);
    // 2: fused gemm0+gemm1 (first) + trailing independent count blocks (r7 ordering)
    k_cg01e<<<dim3(gb + nCB), dim3(256), 0, stream>>>(
        x, (const uint4*)wf, (const uint4*)(wf + (size_t)32768),
        in_g, in_b, lin_b, bn0_g, bn0_b, hbuf, hwbA, N, gb,
        esrc, edst, cnt, slots, E);
    // 3: agg layer-1 (scales gathered rows by dis[src] from cnt) -> h1 (fp32 + bf16)
    k_agg1<<<dim3((N + 3) / 4), dim3(256), 0, stream>>>(
        (const unsigned*)hwbA, hbuf, cnt, slots, cb[0], bg[0], bb[0], (uint4*)hb16, N);
    // 4: gemm layer-2 (dis-prescaled; cnt ready)
    k_gemmb<<<dim3(gb), dim3(256), 0, stream>>>(
        (const uint4*)hb16, (const uint4*)(wf + (size_t)2 * 32768), cnt, hwbB, N);
    // 5: agg layer-2 -> h2
    k_agg<<<dim3((N + 3) / 4), dim3(256), 0, stream>>>(
        (const unsigned*)hwbB, hbuf, cnt, slots, cb[1], bg[1], bb[1], (uint4*)hb16, N);
    // 6: gemm layer-3
    k_gemmb<<<dim3(gb), dim3(256), 0, stream>>>(
        (const uint4*)hb16, (const uint4*)(wf + (size_t)3 * 32768), cnt, hwbA, N);
    // 7: agg layer-3 -> bf16 h3 only
    k_agg3<<<dim3((N + 3) / 4), dim3(256), 0, stream>>>(
        (const unsigned*)hwbA, hbuf, cnt, slots, cb[2], bg[2], bb[2], (uint4*)hb16, N);
    // 8: heads — 2D grid, 5 heads x 256 game-blocks
    k_headmm<<<dim3((G + 63) / 64, 5), dim3(256), 0, stream>>>(
        (const uint4*)hb16, gidx, (const uint4*)p1, (const uint4*)p2,
        hb1, hg1, hbb1, hb2, hW3, hb3,
        ob1, og1, obb1, ob2, og2, obb2, oW3, ob3,
        (float*)d_out, G);
}

// Round 11
// 299.530 us; speedup vs baseline: 1.4847x; 1.0768x over previous
//
#include <hip/hip_runtime.h>
#include <hip/hip_bf16.h>

#define HDIM 128
#define PAD 64
static constexpr float BN_S = 0.99999500003749968751f; // 1/sqrt(1+1e-5)

typedef float f32x4 __attribute__((ext_vector_type(4)));
typedef short s16x8 __attribute__((ext_vector_type(8)));

union U128 { uint4 u; s16x8 s; };

__device__ __forceinline__ unsigned short f2bs(float f){
    union{float f; unsigned u;} c; c.f = f;
    unsigned r = c.u + 0x7fffu + ((c.u >> 16) & 1u);
    return (unsigned short)(r >> 16);
}
__device__ __forceinline__ float bs2f(unsigned short s){
    union{unsigned u; float f;} c; c.u = ((unsigned)s) << 16;
    return c.f;
}
__device__ __forceinline__ float ulo(unsigned u){ union{unsigned i; float f;} c; c.i = u << 16; return c.f; }
__device__ __forceinline__ float uhi(unsigned u){ union{unsigned i; float f;} c; c.i = u & 0xffff0000u; return c.f; }

// ---------------- prepack all weights (weights only; ~456 blocks, fast) ----------------
__global__ __launch_bounds__(256) void k_prep(
    const float* __restrict__ linW, const float* __restrict__ cW1,
    const float* __restrict__ cW2, const float* __restrict__ cW3,
    const float* __restrict__ hW1, const float* __restrict__ oW1,
    const float* __restrict__ hW2, const float* __restrict__ oW2,
    unsigned short* __restrict__ wf, unsigned short* __restrict__ p1,
    unsigned short* __restrict__ p2)
{
    int id = blockIdx.x * 256 + threadIdx.x;
    if (id < 65536){
        int mat = id >> 14;
        int el = id & 16383;
        int k = el >> 7, n = el & 127;
        const float* W = (mat == 0) ? linW : (mat == 1) ? cW1 : (mat == 2) ? cW2 : cW3;
        float v = W[k * 128 + n];
        unsigned short hs = f2bs(v);
        unsigned short ls = f2bs(v - bs2f(hs));
        int nt = n >> 4, lanen = n & 15, kc = k >> 5, quad = (k >> 3) & 3, j = k & 7;
        int lane = quad * 16 + lanen;
        size_t base = (size_t)mat * 32768;
        wf[base + (size_t)(((nt * 4 + kc) * 2 + 0) * 64 + lane) * 8 + j] = hs;
        wf[base + (size_t)(((nt * 4 + kc) * 2 + 1) * 64 + lane) * 8 + j] = ls;
    } else if (id < 65536 + 51200){
        int id1 = id - 65536;
        if (id1 < 40960){
            int j = id1 & 7, lane = (id1 >> 3) & 63, kc = (id1 >> 9) & 3, nt = (id1 >> 11) & 3, y = id1 >> 13;
            int k = kc * 32 + (lane >> 4) * 8 + j;
            int n = nt * 16 + (lane & 15);
            float w = (y < 4) ? hW1[(y * 128 + k) * 64 + n] : oW1[k * 64 + n];
            p1[id1] = f2bs(w);
        } else {
            int id2 = id1 - 40960;
            int j = id2 & 7, lane = (id2 >> 3) & 63, kc = (id2 >> 9) & 1, nt = (id2 >> 10) & 1, y = id2 >> 11;
            int k = kc * 32 + (lane >> 4) * 8 + j;
            int n = nt * 16 + (lane & 15);
            float w = (y < 4) ? hW2[(y * 64 + k) * 32 + n] : oW2[k * 32 + n];
            p2[id2] = f2bs(w);
        }
    }
}

// ---------------- fused: gemm0+gemm1 blocks (first) + count blocks + flag blocks ----------------
// bid < gb:              gemm tile (r7-proven): gemm0 split-A -> fp32 h; gemm1 -> UNSCALED bf16 hwout.
// gb <= bid < gb+nCB:    count blocks trailing (fill gaps around resident gemm blocks),
//                        1 edge/thread: rank = atomicAdd(cnt[dst]); slots16[dst*PAD+rank] = src.
// bid >= gb+nCB:         flag blocks: flag[gidx[i]] = 1 (nodes needed by the heads).
// All three parts fully independent; no inter-block waiting (round-6 lesson).
__global__ __launch_bounds__(256) void k_cg01e(
    const float* __restrict__ x, const uint4* __restrict__ wf0, const uint4* __restrict__ wf1,
    const float* __restrict__ ing, const float* __restrict__ inb,
    const float* __restrict__ lb, const float* __restrict__ g0, const float* __restrict__ b0,
    float* __restrict__ hout, unsigned short* __restrict__ hwout, int nrows, int gb, int nCB,
    const int* __restrict__ esrc, const int* __restrict__ edst,
    int* __restrict__ cnt, unsigned short* __restrict__ slots, int E,
    const int* __restrict__ gidx, int* __restrict__ flag, int G)
{
    __shared__ __align__(16) unsigned sbuf[64 * 136];
    int bid = blockIdx.x;
    int t = threadIdx.x;

    if (bid >= gb){
        int cb = bid - gb;
        if (cb < nCB){
            int e = cb * 256 + t;
            if (e < E){
                int d = edst[e];
                int r = atomicAdd(&cnt[d], 1);
                if (r < PAD) slots[(size_t)d * PAD + r] = (unsigned short)esrc[e];  // N < 65536
            }
        } else {
            int i = (cb - nCB) * 256 + t;
            if (i < G) flag[gidx[i]] = 1;
        }
        return;
    }

    unsigned* sAhi = sbuf;
    unsigned* sAlo = sbuf + 64 * 68;
    int row0 = bid * 64;
    for (int i = t; i < 2048; i += 256){
        int r = i >> 5, q = i & 31;
        int gr = row0 + r;
        float4 v = make_float4(0.f, 0.f, 0.f, 0.f);
        if (gr < nrows) v = *(const float4*)&x[(size_t)gr * 128 + q * 4];
        float4 g = *(const float4*)&ing[q * 4];
        float4 bo = *(const float4*)&inb[q * 4];
        v.x = v.x * (g.x * BN_S) + bo.x;
        v.y = v.y * (g.y * BN_S) + bo.y;
        v.z = v.z * (g.z * BN_S) + bo.z;
        v.w = v.w * (g.w * BN_S) + bo.w;
        unsigned u0 = __float_as_uint(v.x), u1 = __float_as_uint(v.y);
        unsigned u2 = __float_as_uint(v.z), u3 = __float_as_uint(v.w);
        uint2 hi = make_uint2((u0 >> 16) | (u1 & 0xffff0000u), (u2 >> 16) | (u3 & 0xffff0000u));
        unsigned short l0 = f2bs(v.x - __uint_as_float(u0 & 0xffff0000u));
        unsigned short l1 = f2bs(v.y - __uint_as_float(u1 & 0xffff0000u));
        unsigned short l2 = f2bs(v.z - __uint_as_float(u2 & 0xffff0000u));
        unsigned short l3 = f2bs(v.w - __uint_as_float(u3 & 0xffff0000u));
        uint2 lo = make_uint2((unsigned)l0 | ((unsigned)l1 << 16), (unsigned)l2 | ((unsigned)l3 << 16));
        *(uint2*)&sAhi[r * 68 + q * 2] = hi;
        *(uint2*)&sAlo[r * 68 + q * 2] = lo;
    }
    __syncthreads();

    int w = t >> 6, l = t & 63;
    int lanen = l & 15, quad = l >> 4;
    int mrow = w * 16 + lanen;
    f32x4 acc[8];
#pragma unroll
    for (int i = 0; i < 8; ++i) acc[i] = (f32x4){0.f, 0.f, 0.f, 0.f};

#pragma unroll 1
    for (int kc = 0; kc < 4; ++kc){
        U128 ahi, alo;
        ahi.u = *(const uint4*)&sAhi[mrow * 68 + kc * 16 + quad * 4];
        alo.u = *(const uint4*)&sAlo[mrow * 68 + kc * 16 + quad * 4];
        U128 whi[8];
#pragma unroll
        for (int nt = 0; nt < 8; ++nt)
            whi[nt].u = wf0[((nt * 4 + kc) * 2 + 0) * 64 + l];
#pragma unroll
        for (int nt = 0; nt < 8; ++nt)
            acc[nt] = __builtin_amdgcn_mfma_f32_16x16x32_bf16(ahi.s, whi[nt].s, acc[nt], 0, 0, 0);
#pragma unroll
        for (int nt = 0; nt < 8; ++nt)
            acc[nt] = __builtin_amdgcn_mfma_f32_16x16x32_bf16(alo.s, whi[nt].s, acc[nt], 0, 0, 0);
    }

    // epilogue gemm0: h tile -> LDS (f32, stride 132), coalesced fp32 global write
    __syncthreads();
    float* so = (float*)sbuf;
#pragma unroll
    for (int nt = 0; nt < 8; ++nt){
        int n = nt * 16 + lanen;
        float bias = lb[n], g = g0[n], bo = b0[n];
#pragma unroll
        for (int r = 0; r < 4; ++r){
            int row = w * 16 + quad * 4 + r;
            float v = g * ((acc[nt][r] + bias) * BN_S) + bo;
            so[row * 132 + n] = fmaxf(v, 0.f);
        }
    }
    __syncthreads();
    for (int i = t; i < 2048; i += 256){
        int row = i >> 5, c4 = (i & 31) * 4;
        int grow = row0 + row;
        if (grow < nrows)
            *(float4*)&hout[(size_t)grow * 128 + c4] = *(float4*)&so[row * 132 + c4];
    }

    // gemm1: fragments straight from so (h tile); UNSCALED bf16 out
    f32x4 acc2[8];
#pragma unroll
    for (int i = 0; i < 8; ++i) acc2[i] = (f32x4){0.f, 0.f, 0.f, 0.f};
#pragma unroll 1
    for (int kc = 0; kc < 4; ++kc){
        float4 a0 = *(const float4*)&so[mrow * 132 + kc * 32 + quad * 8];
        float4 a1 = *(const float4*)&so[mrow * 132 + kc * 32 + quad * 8 + 4];
        U128 af;
        af.u.x = (unsigned)f2bs(a0.x) | ((unsigned)f2bs(a0.y) << 16);
        af.u.y = (unsigned)f2bs(a0.z) | ((unsigned)f2bs(a0.w) << 16);
        af.u.z = (unsigned)f2bs(a1.x) | ((unsigned)f2bs(a1.y) << 16);
        af.u.w = (unsigned)f2bs(a1.z) | ((unsigned)f2bs(a1.w) << 16);
        U128 wh[8];
#pragma unroll
        for (int nt = 0; nt < 8; ++nt)
            wh[nt].u = wf1[((nt * 4 + kc) * 2 + 0) * 64 + l];
#pragma unroll
        for (int nt = 0; nt < 8; ++nt)
            acc2[nt] = __builtin_amdgcn_mfma_f32_16x16x32_bf16(af.s, wh[nt].s, acc2[nt], 0, 0, 0);
    }
    __syncthreads();   // all waves done reading so
    unsigned short* ss = (unsigned short*)sbuf;
#pragma unroll
    for (int nt = 0; nt < 8; ++nt){
        int n = nt * 16 + lanen;
#pragma unroll
        for (int r = 0; r < 4; ++r){
            int row = w * 16 + quad * 4 + r;
            ss[row * 136 + n] = f2bs(acc2[nt][r]);
        }
    }
    __syncthreads();
    for (int i = t; i < 1024; i += 256){
        int row = i >> 4, c = i & 15;
        int grow = row0 + row;
        if (grow < nrows)
            *(uint4*)&hwout[(size_t)grow * 128 + c * 8] = *(uint4*)&ss[row * 136 + c * 8];
    }
}

// ---------------- standalone layer gemm: bf16 h in, dis-prescaled bf16 out ----------------
__global__ __launch_bounds__(256) void k_gemmb(
    const uint4* __restrict__ hb16, const uint4* __restrict__ wf,
    const int* __restrict__ cnt,
    unsigned short* __restrict__ hwout, int nrows)
{
    __shared__ __align__(16) unsigned sbuf[64 * 68];
    __shared__ float sdis[64];
    int t = threadIdx.x;
    int row0 = blockIdx.x * 64;
    if (t < 64){
        int gr = row0 + t;
        sdis[t] = (gr < nrows) ? rsqrtf(1.0f + (float)cnt[gr]) : 1.0f;
    }
    for (int i = t; i < 1024; i += 256){
        int r = i >> 4, c = i & 15;
        int gr = row0 + r;
        uint4 v = make_uint4(0u, 0u, 0u, 0u);
        if (gr < nrows) v = hb16[(size_t)gr * 16 + c];
        *(uint4*)&sbuf[r * 68 + c * 4] = v;
    }
    __syncthreads();

    int w = t >> 6, l = t & 63;
    int lanen = l & 15, quad = l >> 4;
    int mrow = w * 16 + lanen;
    f32x4 acc[8];
#pragma unroll
    for (int i = 0; i < 8; ++i) acc[i] = (f32x4){0.f, 0.f, 0.f, 0.f};
#pragma unroll 1
    for (int kc = 0; kc < 4; ++kc){
        U128 ah;
        ah.u = *(const uint4*)&sbuf[mrow * 68 + kc * 16 + quad * 4];
        U128 wh[8];
#pragma unroll
        for (int nt = 0; nt < 8; ++nt)
            wh[nt].u = wf[((nt * 4 + kc) * 2 + 0) * 64 + l];
#pragma unroll
        for (int nt = 0; nt < 8; ++nt)
            acc[nt] = __builtin_amdgcn_mfma_f32_16x16x32_bf16(ah.s, wh[nt].s, acc[nt], 0, 0, 0);
    }
    __syncthreads();
    unsigned short* ss = (unsigned short*)sbuf;
#pragma unroll
    for (int nt = 0; nt < 8; ++nt){
        int n = nt * 16 + lanen;
#pragma unroll
        for (int r = 0; r < 4; ++r){
            int row = w * 16 + quad * 4 + r;
            ss[row * 136 + n] = f2bs(acc[nt][r] * sdis[row]);
        }
    }
    __syncthreads();
    for (int i = t; i < 1024; i += 256){
        int row = i >> 4, c = i & 15;
        int grow = row0 + row;
        if (grow < nrows)
            *(uint4*)&hwout[(size_t)grow * 128 + c * 8] = *(uint4*)&ss[row * 136 + c * 8];
    }
}

// ---------------- padded-slot aggregate (full-row; r7 proven form + flag modes) ----------------
// SCALESRC=1 (layer 1): hwu rows UNSCALED, per-edge coef = dis[src]; self term *dis[row].
// WRITEH=1: write fp32 h (residual) + bf16 h; WRITEH=0 (final layer): bf16 h only.
// FLAGMODE=0: none. FLAGMODE=1: gate fp32-h write on flag[row] (h only needed as
// residual base by the FLAG-gated final agg). FLAGMODE=2: skip entire row if !flag[row]
// (output consumed only by heads, which read flagged nodes only).
template<int WRITEH, int SCALESRC, int FLAGMODE>
__device__ __forceinline__ void agg_body(
    const unsigned* __restrict__ hwu, float* __restrict__ h,
    const int* __restrict__ cnt, const unsigned short* __restrict__ slots,
    const float* __restrict__ cb, const float* __restrict__ bg, const float* __restrict__ bb,
    uint4* __restrict__ hb16o, const int* __restrict__ flag, int N)
{
    int row = blockIdx.x * 4 + (threadIdx.x >> 6);
    if (row >= N) return;
    if (FLAGMODE == 2 && flag[row] == 0) return;
    int l = threadIdx.x & 63;
    int sub = l >> 4, cg = l & 15;
    int c0 = cnt[row];
    int c = (c0 > PAD) ? PAD : c0;
    float acc[8];
#pragma unroll
    for (int i = 0; i < 8; ++i) acc[i] = 0.f;
    for (int p = 0; p < c; p += 16){
        int base = p + sub * 4;
        if (base < c){
            uint2 s2 = *(const uint2*)&slots[(size_t)row * PAD + base];
            int s0 = (int)(s2.x & 0xffffu);
            int t1 = (int)(s2.x >> 16);
            int t2 = (int)(s2.y & 0xffffu);
            int t3 = (int)(s2.y >> 16);
            int i1 = (base + 1 < c) ? t1 : s0;
            int i2 = (base + 2 < c) ? t2 : s0;
            int i3 = (base + 3 < c) ? t3 : s0;
            float cf0, cf1, cf2, cf3;
            if (SCALESRC){
                cf0 = rsqrtf(1.0f + (float)cnt[s0]);
                cf1 = (base + 1 < c) ? rsqrtf(1.0f + (float)cnt[i1]) : 0.f;
                cf2 = (base + 2 < c) ? rsqrtf(1.0f + (float)cnt[i2]) : 0.f;
                cf3 = (base + 3 < c) ? rsqrtf(1.0f + (float)cnt[i3]) : 0.f;
            } else {
                cf0 = 1.f;
                cf1 = (base + 1 < c) ? 1.f : 0.f;
                cf2 = (base + 2 < c) ? 1.f : 0.f;
                cf3 = (base + 3 < c) ? 1.f : 0.f;
            }
            uint4 v0 = *(const uint4*)&hwu[(size_t)s0 * 64 + cg * 4];
            uint4 v1 = *(const uint4*)&hwu[(size_t)i1 * 64 + cg * 4];
            uint4 v2 = *(const uint4*)&hwu[(size_t)i2 * 64 + cg * 4];
            uint4 v3 = *(const uint4*)&hwu[(size_t)i3 * 64 + cg * 4];
            acc[0] = fmaf(ulo(v0.x), cf0, acc[0]); acc[1] = fmaf(uhi(v0.x), cf0, acc[1]);
            acc[2] = fmaf(ulo(v0.y), cf0, acc[2]); acc[3] = fmaf(uhi(v0.y), cf0, acc[3]);
            acc[4] = fmaf(ulo(v0.z), cf0, acc[4]); acc[5] = fmaf(uhi(v0.z), cf0, acc[5]);
            acc[6] = fmaf(ulo(v0.w), cf0, acc[6]); acc[7] = fmaf(uhi(v0.w), cf0, acc[7]);
            acc[0] = fmaf(ulo(v1.x), cf1, acc[0]); acc[1] = fmaf(uhi(v1.x), cf1, acc[1]);
            acc[2] = fmaf(ulo(v1.y), cf1, acc[2]); acc[3] = fmaf(uhi(v1.y), cf1, acc[3]);
            acc[4] = fmaf(ulo(v1.z), cf1, acc[4]); acc[5] = fmaf(uhi(v1.z), cf1, acc[5]);
            acc[6] = fmaf(ulo(v1.w), cf1, acc[6]); acc[7] = fmaf(uhi(v1.w), cf1, acc[7]);
            acc[0] = fmaf(ulo(v2.x), cf2, acc[0]); acc[1] = fmaf(uhi(v2.x), cf2, acc[1]);
            acc[2] = fmaf(ulo(v2.y), cf2, acc[2]); acc[3] = fmaf(uhi(v2.y), cf2, acc[3]);
            acc[4] = fmaf(ulo(v2.z), cf2, acc[4]); acc[5] = fmaf(uhi(v2.z), cf2, acc[5]);
            acc[6] = fmaf(ulo(v2.w), cf2, acc[6]); acc[7] = fmaf(uhi(v2.w), cf2, acc[7]);
            acc[0] = fmaf(ulo(v3.x), cf3, acc[0]); acc[1] = fmaf(uhi(v3.x), cf3, acc[1]);
            acc[2] = fmaf(ulo(v3.y), cf3, acc[2]); acc[3] = fmaf(uhi(v3.y), cf3, acc[3]);
            acc[4] = fmaf(ulo(v3.z), cf3, acc[4]); acc[5] = fmaf(uhi(v3.z), cf3, acc[5]);
            acc[6] = fmaf(ulo(v3.w), cf3, acc[6]); acc[7] = fmaf(uhi(v3.w), cf3, acc[7]);
        }
    }
#pragma unroll
    for (int i = 0; i < 8; ++i){
        acc[i] += __shfl_xor(acc[i], 16);
        acc[i] += __shfl_xor(acc[i], 32);
    }
    if (sub == 0){
        float d = rsqrtf(1.0f + (float)c0);
        float selfs = SCALESRC ? d : 1.f;
        uint4 sv = *(const uint4*)&hwu[(size_t)row * 64 + cg * 4];
        float sf[8] = {ulo(sv.x), uhi(sv.x), ulo(sv.y), uhi(sv.y),
                       ulo(sv.z), uhi(sv.z), ulo(sv.w), uhi(sv.w)};
        float4 c0v = *(const float4*)&cb[cg * 8], c1v = *(const float4*)&cb[cg * 8 + 4];
        float4 g0v = *(const float4*)&bg[cg * 8], g1v = *(const float4*)&bg[cg * 8 + 4];
        float4 b0v = *(const float4*)&bb[cg * 8], b1v = *(const float4*)&bb[cg * 8 + 4];
        float cc[8] = {c0v.x, c0v.y, c0v.z, c0v.w, c1v.x, c1v.y, c1v.z, c1v.w};
        float gg[8] = {g0v.x, g0v.y, g0v.z, g0v.w, g1v.x, g1v.y, g1v.z, g1v.w};
        float bo[8] = {b0v.x, b0v.y, b0v.z, b0v.w, b1v.x, b1v.y, b1v.z, b1v.w};
        float4 cur0 = *(const float4*)&h[(size_t)row * 128 + cg * 8];
        float4 cur1 = *(const float4*)&h[(size_t)row * 128 + cg * 8 + 4];
        float o[8] = {cur0.x, cur0.y, cur0.z, cur0.w, cur1.x, cur1.y, cur1.z, cur1.w};
#pragma unroll
        for (int i = 0; i < 8; ++i){
            float v = gg[i] * (((acc[i] + sf[i] * selfs) * d + cc[i]) * BN_S) + bo[i];
            o[i] += fmaxf(v, 0.f);
        }
        if (WRITEH){
            bool wr = (FLAGMODE != 1) || (flag[row] != 0);
            if (wr){
                *(float4*)&h[(size_t)row * 128 + cg * 8] = make_float4(o[0], o[1], o[2], o[3]);
                *(float4*)&h[(size_t)row * 128 + cg * 8 + 4] = make_float4(o[4], o[5], o[6], o[7]);
            }
        }
        uint4 pk;
        pk.x = (unsigned)f2bs(o[0]) | ((unsigned)f2bs(o[1]) << 16);
        pk.y = (unsigned)f2bs(o[2]) | ((unsigned)f2bs(o[3]) << 16);
        pk.z = (unsigned)f2bs(o[4]) | ((unsigned)f2bs(o[5]) << 16);
        pk.w = (unsigned)f2bs(o[6]) | ((unsigned)f2bs(o[7]) << 16);
        hb16o[(size_t)row * 16 + cg] = pk;
    }
}

__global__ __launch_bounds__(256) void k_agg1(
    const unsigned* __restrict__ hwu, float* __restrict__ h,
    const int* __restrict__ cnt, const unsigned short* __restrict__ slots,
    const float* __restrict__ cb, const float* __restrict__ bg, const float* __restrict__ bb,
    uint4* __restrict__ hb16o, const int* __restrict__ flag, int N)
{
    agg_body<1, 1, 0>(hwu, h, cnt, slots, cb, bg, bb, hb16o, flag, N);
}

__global__ __launch_bounds__(256) void k_agg2(
    const unsigned* __restrict__ hwu, float* __restrict__ h,
    const int* __restrict__ cnt, const unsigned short* __restrict__ slots,
    const float* __restrict__ cb, const float* __restrict__ bg, const float* __restrict__ bb,
    uint4* __restrict__ hb16o, const int* __restrict__ flag, int N)
{
    agg_body<1, 0, 1>(hwu, h, cnt, slots, cb, bg, bb, hb16o, flag, N);
}

__global__ __launch_bounds__(256) void k_agg3(
    const unsigned* __restrict__ hwu, float* __restrict__ h,
    const int* __restrict__ cnt, const unsigned short* __restrict__ slots,
    const float* __restrict__ cb, const float* __restrict__ bg, const float* __restrict__ bb,
    uint4* __restrict__ hb16o, const int* __restrict__ flag, int N)
{
    agg_body<0, 0, 2>(hwu, h, cnt, slots, cb, bg, bb, hb16o, flag, N);
}

// ---------------- MFMA fused heads: 2D grid (y = head), bf16 gather ----------------
__global__ __launch_bounds__(256) void k_headmm(
    const uint4* __restrict__ hb16, const int* __restrict__ gidx,
    const uint4* __restrict__ p1v, const uint4* __restrict__ p2v,
    const float* __restrict__ hb1, const float* __restrict__ hg1, const float* __restrict__ hbb1,
    const float* __restrict__ hb2,
    const float* __restrict__ hW3, const float* __restrict__ hb3,
    const float* __restrict__ ob1, const float* __restrict__ og1, const float* __restrict__ obb1,
    const float* __restrict__ ob2, const float* __restrict__ og2, const float* __restrict__ obb2,
    const float* __restrict__ oW3, const float* __restrict__ ob3,
    float* __restrict__ out, int G)
{
    __shared__ __align__(16) unsigned sxg[64 * 68];
    __shared__ __align__(16) unsigned sz1u[64 * 36];
    __shared__ __align__(16) unsigned sz2u[64 * 20];
    __shared__ float sb1[64], sg1[64], sbb1[64];
    __shared__ float sb2[32], sg2[32], sbb2[32];
    __shared__ float sW3[96];
    __shared__ float sb3[3];
    __shared__ int sgi[64];

    int t = threadIdx.x;
    int gblk = blockIdx.x;
    int y = blockIdx.y;
    bool bn2 = (y == 4);
    int w = t >> 6, l = t & 63;
    int lanen = l & 15, quad = l >> 4;

    const float* b1  = bn2 ? ob1  : (hb1 + y * 64);
    const float* g1  = bn2 ? og1  : (hg1 + y * 64);
    const float* bb1 = bn2 ? obb1 : (hbb1 + y * 64);
    const float* b2  = bn2 ? ob2  : (hb2 + y * 32);
    const float* W3  = bn2 ? oW3  : (hW3 + y * 32);
    const float* b3  = bn2 ? ob3  : (hb3 + y);
    int nc3 = bn2 ? 3 : 1;

    if (t < 64){
        sb1[t] = b1[t]; sg1[t] = g1[t]; sbb1[t] = bb1[t];
        if (t < 3) sb3[t] = (t < nc3) ? b3[t] : 0.f;
    } else if (t < 96){
        int p = t - 64;
        sb2[p] = b2[p];
        sg2[p] = bn2 ? og2[p] : 1.f;
        sbb2[p] = bn2 ? obb2[p] : 0.f;
    } else if (t < 192){
        int i = t - 96;
        sW3[i] = (i < 32 * nc3) ? W3[i] : 0.f;
    } else {
        int r = t - 192;
        int g = gblk * 64 + r;
        sgi[r] = (g < G) ? gidx[g] : 0;
    }
    __syncthreads();
    for (int i = t; i < 1024; i += 256){
        int r = i >> 4, c = i & 15;
        int node = sgi[r];
        uint4 v = hb16[(size_t)node * 16 + c];
        *(uint4*)&sxg[r * 68 + c * 4] = v;
    }
    __syncthreads();

    f32x4 acc1[4] = {{0.f,0.f,0.f,0.f},{0.f,0.f,0.f,0.f},{0.f,0.f,0.f,0.f},{0.f,0.f,0.f,0.f}};
#pragma unroll
    for (int kc = 0; kc < 4; ++kc){
        U128 a;
        a.u = *(const uint4*)&sxg[(w * 16 + lanen) * 68 + kc * 16 + quad * 4];
#pragma unroll
        for (int nt = 0; nt < 4; ++nt){
            U128 bfr;
            bfr.u = p1v[((y * 4 + nt) * 4 + kc) * 64 + l];
            acc1[nt] = __builtin_amdgcn_mfma_f32_16x16x32_bf16(a.s, bfr.s, acc1[nt], 0, 0, 0);
        }
    }
    {
        unsigned short* sz1s = (unsigned short*)sz1u;
#pragma unroll
        for (int nt = 0; nt < 4; ++nt){
            int n = nt * 16 + lanen;
            float g = sg1[n], bia = sb1[n], bt = sbb1[n];
#pragma unroll
            for (int r = 0; r < 4; ++r){
                int row = w * 16 + quad * 4 + r;
                float v = g * ((acc1[nt][r] + bia) * BN_S) + bt;
                sz1s[row * 72 + n] = f2bs(fmaxf(v, 0.f));
            }
        }
    }
    __syncthreads();

    f32x4 acc2[2] = {{0.f,0.f,0.f,0.f},{0.f,0.f,0.f,0.f}};
#pragma unroll
    for (int kc = 0; kc < 2; ++kc){
        U128 a;
        a.u = *(const uint4*)&sz1u[(w * 16 + lanen) * 36 + kc * 16 + quad * 4];
#pragma unroll
        for (int nt = 0; nt < 2; ++nt){
            U128 bfr;
            bfr.u = p2v[((y * 2 + nt) * 2 + kc) * 64 + l];
            acc2[nt] = __builtin_amdgcn_mfma_f32_16x16x32_bf16(a.s, bfr.s, acc2[nt], 0, 0, 0);
        }
    }
    {
        unsigned short* sz2s = (unsigned short*)sz2u;
#pragma unroll
        for (int nt = 0; nt < 2; ++nt){
            int n = nt * 16 + lanen;
            float bia = sb2[n], g = sg2[n], bt = sbb2[n];
#pragma unroll
            for (int r = 0; r < 4; ++r){
                int row = w * 16 + quad * 4 + r;
                float v = acc2[nt][r] + bia;
                if (bn2) v = g * (v * BN_S) + bt;
                sz2s[row * 40 + n] = f2bs(fmaxf(v, 0.f));
            }
        }
    }
    __syncthreads();

    const unsigned short* sz2s = (const unsigned short*)sz2u;
    if (!bn2){
        if (t < 64){
            int g = gblk * 64 + t;
            if (g < G){
                float s = sb3[0];
#pragma unroll
                for (int p = 0; p < 32; ++p) s = fmaf(bs2f(sz2s[t * 40 + p]), sW3[p], s);
                out[(size_t)g * 7 + y] = s;
            }
        }
    } else {
        if (t < 192){
            int gl = t / 3, c = t % 3;
            int g = gblk * 64 + gl;
            if (g < G){
                float s = sb3[c];
#pragma unroll
                for (int p = 0; p < 32; ++p) s = fmaf(bs2f(sz2s[gl * 40 + p]), sW3[p * 3 + c], s);
                out[(size_t)g * 7 + 4 + c] = s;
            }
        }
    }
}

extern "C" void kernel_launch(void* const* d_in, const int* in_sizes, int n_in,
                              void* d_out, int out_size, void* d_ws, size_t ws_size,
                              hipStream_t stream)
{
    const float* x    = (const float*)d_in[0];
    const int* esrc   = (const int*)d_in[1];
    const int* edst   = (const int*)d_in[2];
    const int* gidx   = (const int*)d_in[3];
    const float* in_g = (const float*)d_in[4];
    const float* in_b = (const float*)d_in[5];
    const float* lin_W = (const float*)d_in[6];
    const float* lin_b = (const float*)d_in[7];
    const float* bn0_g = (const float*)d_in[8];
    const float* bn0_b = (const float*)d_in[9];
    const float* cW[3] = {(const float*)d_in[10], (const float*)d_in[14], (const float*)d_in[18]};
    const float* cb[3] = {(const float*)d_in[11], (const float*)d_in[15], (const float*)d_in[19]};
    const float* bg[3] = {(const float*)d_in[12], (const float*)d_in[16], (const float*)d_in[20]};
    const float* bb[3] = {(const float*)d_in[13], (const float*)d_in[17], (const float*)d_in[21]};
    const float* hW1 = (const float*)d_in[22];
    const float* hb1 = (const float*)d_in[23];
    const float* hg1 = (const float*)d_in[24];
    const float* hbb1 = (const float*)d_in[25];
    const float* hW2 = (const float*)d_in[26];
    const float* hb2 = (const float*)d_in[27];
    const float* hW3 = (const float*)d_in[28];
    const float* hb3 = (const float*)d_in[29];
    const float* oW1 = (const float*)d_in[30];
    const float* ob1 = (const float*)d_in[31];
    const float* og1 = (const float*)d_in[32];
    const float* obb1 = (const float*)d_in[33];
    const float* oW2 = (const float*)d_in[34];
    const float* ob2 = (const float*)d_in[35];
    const float* og2 = (const float*)d_in[36];
    const float* obb2 = (const float*)d_in[37];
    const float* oW3 = (const float*)d_in[38];
    const float* ob3 = (const float*)d_in[39];

    const int N = in_sizes[0] / HDIM;
    const int E = in_sizes[1];
    const int G = in_sizes[3];

    char* wsp = (char*)d_ws;
    size_t off = 0;
    auto alloc = [&](size_t bytes) -> char* {
        char* p = wsp + off;
        off = (off + bytes + 255) & ~(size_t)255;
        return p;
    };
    int* cnt      = (int*)alloc((size_t)(2 * N) * 4);   // cnt[N] then flag[N]
    int* flag     = cnt + N;
    unsigned short* slots = (unsigned short*)alloc((size_t)N * PAD * 2);
    float* hbuf   = (float*)alloc((size_t)N * HDIM * 4);
    unsigned short* hwbA = (unsigned short*)alloc((size_t)N * HDIM * 2);
    unsigned short* hwbB = (unsigned short*)alloc((size_t)N * HDIM * 2);
    unsigned short* hb16 = (unsigned short*)alloc((size_t)N * HDIM * 2);
    unsigned short* p1 = (unsigned short*)alloc(40960 * 2);
    unsigned short* p2 = (unsigned short*)alloc(10240 * 2);
    unsigned short* wf = (unsigned short*)alloc((size_t)4 * 32768 * 2);

    int gb = (N + 63) / 64;
    int nCB = (E + 255) / 256;
    int nFB = (G + 255) / 256;

    // 0: zero counters + flags (one fill)
    hipMemsetAsync(cnt, 0, (size_t)(2 * N) * 4, stream);
    // 1: prepack weights
    k_prep<<<dim3((65536 + 51200 + 255) / 256), dim3(256), 0, stream>>>(
        lin_W, cW[0], cW[1], cW[2], hW1, oW1, hW2, oW2, wf, p1, p2);
    // 2: fused gemm0+gemm1 (first) + trailing count blocks + flag blocks (r7 ordering)
    k_cg01e<<<dim3(gb + nCB + nFB), dim3(256), 0, stream>>>(
        x, (const uint4*)wf, (const uint4*)(wf + (size_t)32768),
        in_g, in_b, lin_b, bn0_g, bn0_b, hbuf, hwbA, N, gb, nCB,
        esrc, edst, cnt, slots, E, gidx, flag, G);
    // 3: agg layer-1 (scales gathered rows by dis[src] from cnt) -> h1 (fp32 + bf16)
    k_agg1<<<dim3((N + 3) / 4), dim3(256), 0, stream>>>(
        (const unsigned*)hwbA, hbuf, cnt, slots, cb[0], bg[0], bb[0], (uint4*)hb16, flag, N);
    // 4: gemm layer-2 (dis-prescaled; cnt ready)
    k_gemmb<<<dim3(gb), dim3(256), 0, stream>>>(
        (const uint4*)hb16, (const uint4*)(wf + (size_t)2 * 32768), cnt, hwbB, N);
    // 5: agg layer-2 -> h2 (fp32 h write gated on flag; bf16 for all rows)
    k_agg2<<<dim3((N + 3) / 4), dim3(256), 0, stream>>>(
        (const unsigned*)hwbB, hbuf, cnt, slots, cb[1], bg[1], bb[1], (uint4*)hb16, flag, N);
    // 6: gemm layer-3
    k_gemmb<<<dim3(gb), dim3(256), 0, stream>>>(
        (const uint4*)hb16, (const uint4*)(wf + (size_t)3 * 32768), cnt, hwbA, N);
    // 7: agg layer-3 -> bf16 h3, FLAGGED ROWS ONLY (heads read only gidx nodes)
    k_agg3<<<dim3((N + 3) / 4), dim3(256), 0, stream>>>(
        (const unsigned*)hwbA, hbuf, cnt, slots, cb[2], bg[2], bb[2], (uint4*)hb16, flag, N);
    // 8: heads — 2D grid, 5 heads x 256 game-blocks
    k_headmm<<<dim3((G + 63) / 64, 5), dim3(256), 0, stream>>>(
        (const uint4*)hb16, gidx, (const uint4*)p1, (const uint4*)p2,
        hb1, hg1, hbb1, hb2, hW3, hb3,
        ob1, og1, obb1, ob2, og2, obb2, oW3, ob3,
        (float*)d_out, G);
}

// Round 12
// 298.618 us; speedup vs baseline: 1.4892x; 1.0031x over previous
//
#include <hip/hip_runtime.h>
#include <hip/hip_bf16.h>

#define HDIM 128
#define PAD 64
static constexpr float BN_S = 0.99999500003749968751f; // 1/sqrt(1+1e-5)

typedef float f32x4 __attribute__((ext_vector_type(4)));
typedef short s16x8 __attribute__((ext_vector_type(8)));

union U128 { uint4 u; s16x8 s; };

__device__ __forceinline__ unsigned short f2bs(float f){
    union{float f; unsigned u;} c; c.f = f;
    unsigned r = c.u + 0x7fffu + ((c.u >> 16) & 1u);
    return (unsigned short)(r >> 16);
}
__device__ __forceinline__ float bs2f(unsigned short s){
    union{unsigned u; float f;} c; c.u = ((unsigned)s) << 16;
    return c.f;
}
__device__ __forceinline__ float ulo(unsigned u){ union{unsigned i; float f;} c; c.i = u << 16; return c.f; }
__device__ __forceinline__ float uhi(unsigned u){ union{unsigned i; float f;} c; c.i = u & 0xffff0000u; return c.f; }

// ---------------- minimal serial prefix: wf0/wf1 prepack + cnt/flag zero ----------------
// Only wf0 (linW) and wf1 (cW1) are needed by k_cg01e's gemm blocks; everything else
// (wf2, wf3, p1, p2) is packed by independent trailing blocks inside k_cg01e.
__global__ __launch_bounds__(256) void k_prep0(
    const float* __restrict__ linW, const float* __restrict__ cW1,
    unsigned short* __restrict__ wf, int* __restrict__ cnt, int N2)
{
    int id = blockIdx.x * 256 + threadIdx.x;
    if (id < 32768){
        int mat = id >> 14;      // 0 or 1
        int el = id & 16383;
        int k = el >> 7, n = el & 127;
        const float* W = (mat == 0) ? linW : cW1;
        float v = W[k * 128 + n];
        unsigned short hs = f2bs(v);
        unsigned short ls = f2bs(v - bs2f(hs));
        int nt = n >> 4, lanen = n & 15, kc = k >> 5, quad = (k >> 3) & 3, j = k & 7;
        int lane = quad * 16 + lanen;
        size_t base = (size_t)mat * 32768;
        wf[base + (size_t)(((nt * 4 + kc) * 2 + 0) * 64 + lane) * 8 + j] = hs;
        wf[base + (size_t)(((nt * 4 + kc) * 2 + 1) * 64 + lane) * 8 + j] = ls;
    } else {
        int z = id - 32768;
        if (z < N2) cnt[z] = 0;   // cnt[N] then flag[N], contiguous
    }
}

// ---------------- fused: gemm0+gemm1 + count + flag + rest-of-prepack (all independent) ----------------
// bid < gb:                      gemm tile (r7-proven): gemm0 split-A -> fp32 h; gemm1 -> UNSCALED bf16 hwout.
// gb <= bid < gb+nCB:            count blocks: rank = atomicAdd(cnt[dst]); slots16[dst*PAD+rank] = src.
// gb+nCB <= bid < gb+nCB+nFB:    flag blocks: flag[gidx[i]] = 1.
// bid >= gb+nCB+nFB:             rest-prepack: wf2, wf3 (cW2,cW3) and p1, p2 (head weights) —
//                                first consumed at dispatch 4+ so packing them here hides
//                                under the gemm stream. No inter-block waiting anywhere.
__global__ __launch_bounds__(256) void k_cg01e(
    const float* __restrict__ x, const uint4* __restrict__ wf0, const uint4* __restrict__ wf1,
    const float* __restrict__ ing, const float* __restrict__ inb,
    const float* __restrict__ lb, const float* __restrict__ g0, const float* __restrict__ b0,
    float* __restrict__ hout, unsigned short* __restrict__ hwout, int nrows, int gb, int nCB, int nFB,
    const int* __restrict__ esrc, const int* __restrict__ edst,
    int* __restrict__ cnt, unsigned short* __restrict__ slots, int E,
    const int* __restrict__ gidx, int* __restrict__ flag, int G,
    const float* __restrict__ cW2, const float* __restrict__ cW3,
    const float* __restrict__ hW1, const float* __restrict__ oW1,
    const float* __restrict__ hW2, const float* __restrict__ oW2,
    unsigned short* __restrict__ wfw, unsigned short* __restrict__ p1,
    unsigned short* __restrict__ p2)
{
    __shared__ __align__(16) unsigned sbuf[64 * 136];
    int bid = blockIdx.x;
    int t = threadIdx.x;

    if (bid >= gb){
        int cb = bid - gb;
        if (cb < nCB){
            int e = cb * 256 + t;
            if (e < E){
                int d = edst[e];
                int r = atomicAdd(&cnt[d], 1);
                if (r < PAD) slots[(size_t)d * PAD + r] = (unsigned short)esrc[e];  // N < 65536
            }
        } else if (cb < nCB + nFB){
            int i = (cb - nCB) * 256 + t;
            if (i < G) flag[gidx[i]] = 1;
        } else {
            int idx = (cb - nCB - nFB) * 256 + t;
            if (idx < 32768){
                int mat = 2 + (idx >> 14);
                int el = idx & 16383;
                int k = el >> 7, n = el & 127;
                const float* W = (mat == 2) ? cW2 : cW3;
                float v = W[k * 128 + n];
                unsigned short hs = f2bs(v);
                unsigned short ls = f2bs(v - bs2f(hs));
                int nt = n >> 4, lanen = n & 15, kc = k >> 5, quad = (k >> 3) & 3, j = k & 7;
                int lane = quad * 16 + lanen;
                size_t base = (size_t)mat * 32768;
                wfw[base + (size_t)(((nt * 4 + kc) * 2 + 0) * 64 + lane) * 8 + j] = hs;
                wfw[base + (size_t)(((nt * 4 + kc) * 2 + 1) * 64 + lane) * 8 + j] = ls;
            } else if (idx < 32768 + 51200){
                int id1 = idx - 32768;
                if (id1 < 40960){
                    int j = id1 & 7, lane = (id1 >> 3) & 63, kc = (id1 >> 9) & 3, nt = (id1 >> 11) & 3, y = id1 >> 13;
                    int k = kc * 32 + (lane >> 4) * 8 + j;
                    int n = nt * 16 + (lane & 15);
                    float w = (y < 4) ? hW1[(y * 128 + k) * 64 + n] : oW1[k * 64 + n];
                    p1[id1] = f2bs(w);
                } else {
                    int id2 = id1 - 40960;
                    int j = id2 & 7, lane = (id2 >> 3) & 63, kc = (id2 >> 9) & 1, nt = (id2 >> 10) & 1, y = id2 >> 11;
                    int k = kc * 32 + (lane >> 4) * 8 + j;
                    int n = nt * 16 + (lane & 15);
                    float w = (y < 4) ? hW2[(y * 64 + k) * 32 + n] : oW2[k * 32 + n];
                    p2[id2] = f2bs(w);
                }
            }
        }
        return;
    }

    unsigned* sAhi = sbuf;
    unsigned* sAlo = sbuf + 64 * 68;
    int row0 = bid * 64;
    for (int i = t; i < 2048; i += 256){
        int r = i >> 5, q = i & 31;
        int gr = row0 + r;
        float4 v = make_float4(0.f, 0.f, 0.f, 0.f);
        if (gr < nrows) v = *(const float4*)&x[(size_t)gr * 128 + q * 4];
        float4 g = *(const float4*)&ing[q * 4];
        float4 bo = *(const float4*)&inb[q * 4];
        v.x = v.x * (g.x * BN_S) + bo.x;
        v.y = v.y * (g.y * BN_S) + bo.y;
        v.z = v.z * (g.z * BN_S) + bo.z;
        v.w = v.w * (g.w * BN_S) + bo.w;
        unsigned u0 = __float_as_uint(v.x), u1 = __float_as_uint(v.y);
        unsigned u2 = __float_as_uint(v.z), u3 = __float_as_uint(v.w);
        uint2 hi = make_uint2((u0 >> 16) | (u1 & 0xffff0000u), (u2 >> 16) | (u3 & 0xffff0000u));
        unsigned short l0 = f2bs(v.x - __uint_as_float(u0 & 0xffff0000u));
        unsigned short l1 = f2bs(v.y - __uint_as_float(u1 & 0xffff0000u));
        unsigned short l2 = f2bs(v.z - __uint_as_float(u2 & 0xffff0000u));
        unsigned short l3 = f2bs(v.w - __uint_as_float(u3 & 0xffff0000u));
        uint2 lo = make_uint2((unsigned)l0 | ((unsigned)l1 << 16), (unsigned)l2 | ((unsigned)l3 << 16));
        *(uint2*)&sAhi[r * 68 + q * 2] = hi;
        *(uint2*)&sAlo[r * 68 + q * 2] = lo;
    }
    __syncthreads();

    int w = t >> 6, l = t & 63;
    int lanen = l & 15, quad = l >> 4;
    int mrow = w * 16 + lanen;
    f32x4 acc[8];
#pragma unroll
    for (int i = 0; i < 8; ++i) acc[i] = (f32x4){0.f, 0.f, 0.f, 0.f};

#pragma unroll 1
    for (int kc = 0; kc < 4; ++kc){
        U128 ahi, alo;
        ahi.u = *(const uint4*)&sAhi[mrow * 68 + kc * 16 + quad * 4];
        alo.u = *(const uint4*)&sAlo[mrow * 68 + kc * 16 + quad * 4];
        U128 whi[8];
#pragma unroll
        for (int nt = 0; nt < 8; ++nt)
            whi[nt].u = wf0[((nt * 4 + kc) * 2 + 0) * 64 + l];
#pragma unroll
        for (int nt = 0; nt < 8; ++nt)
            acc[nt] = __builtin_amdgcn_mfma_f32_16x16x32_bf16(ahi.s, whi[nt].s, acc[nt], 0, 0, 0);
#pragma unroll
        for (int nt = 0; nt < 8; ++nt)
            acc[nt] = __builtin_amdgcn_mfma_f32_16x16x32_bf16(alo.s, whi[nt].s, acc[nt], 0, 0, 0);
    }

    // epilogue gemm0: h tile -> LDS (f32, stride 132), coalesced fp32 global write
    __syncthreads();
    float* so = (float*)sbuf;
#pragma unroll
    for (int nt = 0; nt < 8; ++nt){
        int n = nt * 16 + lanen;
        float bias = lb[n], g = g0[n], bo = b0[n];
#pragma unroll
        for (int r = 0; r < 4; ++r){
            int row = w * 16 + quad * 4 + r;
            float v = g * ((acc[nt][r] + bias) * BN_S) + bo;
            so[row * 132 + n] = fmaxf(v, 0.f);
        }
    }
    __syncthreads();
    for (int i = t; i < 2048; i += 256){
        int row = i >> 5, c4 = (i & 31) * 4;
        int grow = row0 + row;
        if (grow < nrows)
            *(float4*)&hout[(size_t)grow * 128 + c4] = *(float4*)&so[row * 132 + c4];
    }

    // gemm1: fragments straight from so (h tile); UNSCALED bf16 out
    f32x4 acc2[8];
#pragma unroll
    for (int i = 0; i < 8; ++i) acc2[i] = (f32x4){0.f, 0.f, 0.f, 0.f};
#pragma unroll 1
    for (int kc = 0; kc < 4; ++kc){
        float4 a0 = *(const float4*)&so[mrow * 132 + kc * 32 + quad * 8];
        float4 a1 = *(const float4*)&so[mrow * 132 + kc * 32 + quad * 8 + 4];
        U128 af;
        af.u.x = (unsigned)f2bs(a0.x) | ((unsigned)f2bs(a0.y) << 16);
        af.u.y = (unsigned)f2bs(a0.z) | ((unsigned)f2bs(a0.w) << 16);
        af.u.z = (unsigned)f2bs(a1.x) | ((unsigned)f2bs(a1.y) << 16);
        af.u.w = (unsigned)f2bs(a1.z) | ((unsigned)f2bs(a1.w) << 16);
        U128 wh[8];
#pragma unroll
        for (int nt = 0; nt < 8; ++nt)
            wh[nt].u = wf1[((nt * 4 + kc) * 2 + 0) * 64 + l];
#pragma unroll
        for (int nt = 0; nt < 8; ++nt)
            acc2[nt] = __builtin_amdgcn_mfma_f32_16x16x32_bf16(af.s, wh[nt].s, acc2[nt], 0, 0, 0);
    }
    __syncthreads();   // all waves done reading so
    unsigned short* ss = (unsigned short*)sbuf;
#pragma unroll
    for (int nt = 0; nt < 8; ++nt){
        int n = nt * 16 + lanen;
#pragma unroll
        for (int r = 0; r < 4; ++r){
            int row = w * 16 + quad * 4 + r;
            ss[row * 136 + n] = f2bs(acc2[nt][r]);
        }
    }
    __syncthreads();
    for (int i = t; i < 1024; i += 256){
        int row = i >> 4, c = i & 15;
        int grow = row0 + row;
        if (grow < nrows)
            *(uint4*)&hwout[(size_t)grow * 128 + c * 8] = *(uint4*)&ss[row * 136 + c * 8];
    }
}

// ---------------- standalone layer gemm: bf16 h in, dis-prescaled bf16 out ----------------
__global__ __launch_bounds__(256) void k_gemmb(
    const uint4* __restrict__ hb16, const uint4* __restrict__ wf,
    const int* __restrict__ cnt,
    unsigned short* __restrict__ hwout, int nrows)
{
    __shared__ __align__(16) unsigned sbuf[64 * 68];
    __shared__ float sdis[64];
    int t = threadIdx.x;
    int row0 = blockIdx.x * 64;
    if (t < 64){
        int gr = row0 + t;
        sdis[t] = (gr < nrows) ? rsqrtf(1.0f + (float)cnt[gr]) : 1.0f;
    }
    for (int i = t; i < 1024; i += 256){
        int r = i >> 4, c = i & 15;
        int gr = row0 + r;
        uint4 v = make_uint4(0u, 0u, 0u, 0u);
        if (gr < nrows) v = hb16[(size_t)gr * 16 + c];
        *(uint4*)&sbuf[r * 68 + c * 4] = v;
    }
    __syncthreads();

    int w = t >> 6, l = t & 63;
    int lanen = l & 15, quad = l >> 4;
    int mrow = w * 16 + lanen;
    f32x4 acc[8];
#pragma unroll
    for (int i = 0; i < 8; ++i) acc[i] = (f32x4){0.f, 0.f, 0.f, 0.f};
#pragma unroll 1
    for (int kc = 0; kc < 4; ++kc){
        U128 ah;
        ah.u = *(const uint4*)&sbuf[mrow * 68 + kc * 16 + quad * 4];
        U128 wh[8];
#pragma unroll
        for (int nt = 0; nt < 8; ++nt)
            wh[nt].u = wf[((nt * 4 + kc) * 2 + 0) * 64 + l];
#pragma unroll
        for (int nt = 0; nt < 8; ++nt)
            acc[nt] = __builtin_amdgcn_mfma_f32_16x16x32_bf16(ah.s, wh[nt].s, acc[nt], 0, 0, 0);
    }
    __syncthreads();
    unsigned short* ss = (unsigned short*)sbuf;
#pragma unroll
    for (int nt = 0; nt < 8; ++nt){
        int n = nt * 16 + lanen;
#pragma unroll
        for (int r = 0; r < 4; ++r){
            int row = w * 16 + quad * 4 + r;
            ss[row * 136 + n] = f2bs(acc[nt][r] * sdis[row]);
        }
    }
    __syncthreads();
    for (int i = t; i < 1024; i += 256){
        int row = i >> 4, c = i & 15;
        int grow = row0 + row;
        if (grow < nrows)
            *(uint4*)&hwout[(size_t)grow * 128 + c * 8] = *(uint4*)&ss[row * 136 + c * 8];
    }
}

// ---------------- padded-slot aggregate (full-row; r7 proven form + flag modes) ----------------
// SCALESRC=1 (layer 1): hwu rows UNSCALED, per-edge coef = dis[src]; self term *dis[row].
// WRITEH=1: write fp32 h (residual) + bf16 h; WRITEH=0 (final layer): bf16 h only.
// FLAGMODE=0: none. FLAGMODE=1: gate fp32-h write on flag[row]. FLAGMODE=2: skip row if !flag.
template<int WRITEH, int SCALESRC, int FLAGMODE>
__device__ __forceinline__ void agg_body(
    const unsigned* __restrict__ hwu, float* __restrict__ h,
    const int* __restrict__ cnt, const unsigned short* __restrict__ slots,
    const float* __restrict__ cb, const float* __restrict__ bg, const float* __restrict__ bb,
    uint4* __restrict__ hb16o, const int* __restrict__ flag, int N)
{
    int row = blockIdx.x * 4 + (threadIdx.x >> 6);
    if (row >= N) return;
    if (FLAGMODE == 2 && flag[row] == 0) return;
    int l = threadIdx.x & 63;
    int sub = l >> 4, cg = l & 15;
    int c0 = cnt[row];
    int c = (c0 > PAD) ? PAD : c0;
    float acc[8];
#pragma unroll
    for (int i = 0; i < 8; ++i) acc[i] = 0.f;
    for (int p = 0; p < c; p += 16){
        int base = p + sub * 4;
        if (base < c){
            uint2 s2 = *(const uint2*)&slots[(size_t)row * PAD + base];
            int s0 = (int)(s2.x & 0xffffu);
            int t1 = (int)(s2.x >> 16);
            int t2 = (int)(s2.y & 0xffffu);
            int t3 = (int)(s2.y >> 16);
            int i1 = (base + 1 < c) ? t1 : s0;
            int i2 = (base + 2 < c) ? t2 : s0;
            int i3 = (base + 3 < c) ? t3 : s0;
            float cf0, cf1, cf2, cf3;
            if (SCALESRC){
                cf0 = rsqrtf(1.0f + (float)cnt[s0]);
                cf1 = (base + 1 < c) ? rsqrtf(1.0f + (float)cnt[i1]) : 0.f;
                cf2 = (base + 2 < c) ? rsqrtf(1.0f + (float)cnt[i2]) : 0.f;
                cf3 = (base + 3 < c) ? rsqrtf(1.0f + (float)cnt[i3]) : 0.f;
            } else {
                cf0 = 1.f;
                cf1 = (base + 1 < c) ? 1.f : 0.f;
                cf2 = (base + 2 < c) ? 1.f : 0.f;
                cf3 = (base + 3 < c) ? 1.f : 0.f;
            }
            uint4 v0 = *(const uint4*)&hwu[(size_t)s0 * 64 + cg * 4];
            uint4 v1 = *(const uint4*)&hwu[(size_t)i1 * 64 + cg * 4];
            uint4 v2 = *(const uint4*)&hwu[(size_t)i2 * 64 + cg * 4];
            uint4 v3 = *(const uint4*)&hwu[(size_t)i3 * 64 + cg * 4];
            acc[0] = fmaf(ulo(v0.x), cf0, acc[0]); acc[1] = fmaf(uhi(v0.x), cf0, acc[1]);
            acc[2] = fmaf(ulo(v0.y), cf0, acc[2]); acc[3] = fmaf(uhi(v0.y), cf0, acc[3]);
            acc[4] = fmaf(ulo(v0.z), cf0, acc[4]); acc[5] = fmaf(uhi(v0.z), cf0, acc[5]);
            acc[6] = fmaf(ulo(v0.w), cf0, acc[6]); acc[7] = fmaf(uhi(v0.w), cf0, acc[7]);
            acc[0] = fmaf(ulo(v1.x), cf1, acc[0]); acc[1] = fmaf(uhi(v1.x), cf1, acc[1]);
            acc[2] = fmaf(ulo(v1.y), cf1, acc[2]); acc[3] = fmaf(uhi(v1.y), cf1, acc[3]);
            acc[4] = fmaf(ulo(v1.z), cf1, acc[4]); acc[5] = fmaf(uhi(v1.z), cf1, acc[5]);
            acc[6] = fmaf(ulo(v1.w), cf1, acc[6]); acc[7] = fmaf(uhi(v1.w), cf1, acc[7]);
            acc[0] = fmaf(ulo(v2.x), cf2, acc[0]); acc[1] = fmaf(uhi(v2.x), cf2, acc[1]);
            acc[2] = fmaf(ulo(v2.y), cf2, acc[2]); acc[3] = fmaf(uhi(v2.y), cf2, acc[3]);
            acc[4] = fmaf(ulo(v2.z), cf2, acc[4]); acc[5] = fmaf(uhi(v2.z), cf2, acc[5]);
            acc[6] = fmaf(ulo(v2.w), cf2, acc[6]); acc[7] = fmaf(uhi(v2.w), cf2, acc[7]);
            acc[0] = fmaf(ulo(v3.x), cf3, acc[0]); acc[1] = fmaf(uhi(v3.x), cf3, acc[1]);
            acc[2] = fmaf(ulo(v3.y), cf3, acc[2]); acc[3] = fmaf(uhi(v3.y), cf3, acc[3]);
            acc[4] = fmaf(ulo(v3.z), cf3, acc[4]); acc[5] = fmaf(uhi(v3.z), cf3, acc[5]);
            acc[6] = fmaf(ulo(v3.w), cf3, acc[6]); acc[7] = fmaf(uhi(v3.w), cf3, acc[7]);
        }
    }
#pragma unroll
    for (int i = 0; i < 8; ++i){
        acc[i] += __shfl_xor(acc[i], 16);
        acc[i] += __shfl_xor(acc[i], 32);
    }
    if (sub == 0){
        float d = rsqrtf(1.0f + (float)c0);
        float selfs = SCALESRC ? d : 1.f;
        uint4 sv = *(const uint4*)&hwu[(size_t)row * 64 + cg * 4];
        float sf[8] = {ulo(sv.x), uhi(sv.x), ulo(sv.y), uhi(sv.y),
                       ulo(sv.z), uhi(sv.z), ulo(sv.w), uhi(sv.w)};
        float4 c0v = *(const float4*)&cb[cg * 8], c1v = *(const float4*)&cb[cg * 8 + 4];
        float4 g0v = *(const float4*)&bg[cg * 8], g1v = *(const float4*)&bg[cg * 8 + 4];
        float4 b0v = *(const float4*)&bb[cg * 8], b1v = *(const float4*)&bb[cg * 8 + 4];
        float cc[8] = {c0v.x, c0v.y, c0v.z, c0v.w, c1v.x, c1v.y, c1v.z, c1v.w};
        float gg[8] = {g0v.x, g0v.y, g0v.z, g0v.w, g1v.x, g1v.y, g1v.z, g1v.w};
        float bo[8] = {b0v.x, b0v.y, b0v.z, b0v.w, b1v.x, b1v.y, b1v.z, b1v.w};
        float4 cur0 = *(const float4*)&h[(size_t)row * 128 + cg * 8];
        float4 cur1 = *(const float4*)&h[(size_t)row * 128 + cg * 8 + 4];
        float o[8] = {cur0.x, cur0.y, cur0.z, cur0.w, cur1.x, cur1.y, cur1.z, cur1.w};
#pragma unroll
        for (int i = 0; i < 8; ++i){
            float v = gg[i] * (((acc[i] + sf[i] * selfs) * d + cc[i]) * BN_S) + bo[i];
            o[i] += fmaxf(v, 0.f);
        }
        if (WRITEH){
            bool wr = (FLAGMODE != 1) || (flag[row] != 0);
            if (wr){
                *(float4*)&h[(size_t)row * 128 + cg * 8] = make_float4(o[0], o[1], o[2], o[3]);
                *(float4*)&h[(size_t)row * 128 + cg * 8 + 4] = make_float4(o[4], o[5], o[6], o[7]);
            }
        }
        uint4 pk;
        pk.x = (unsigned)f2bs(o[0]) | ((unsigned)f2bs(o[1]) << 16);
        pk.y = (unsigned)f2bs(o[2]) | ((unsigned)f2bs(o[3]) << 16);
        pk.z = (unsigned)f2bs(o[4]) | ((unsigned)f2bs(o[5]) << 16);
        pk.w = (unsigned)f2bs(o[6]) | ((unsigned)f2bs(o[7]) << 16);
        hb16o[(size_t)row * 16 + cg] = pk;
    }
}

__global__ __launch_bounds__(256) void k_agg1(
    const unsigned* __restrict__ hwu, float* __restrict__ h,
    const int* __restrict__ cnt, const unsigned short* __restrict__ slots,
    const float* __restrict__ cb, const float* __restrict__ bg, const float* __restrict__ bb,
    uint4* __restrict__ hb16o, const int* __restrict__ flag, int N)
{
    agg_body<1, 1, 0>(hwu, h, cnt, slots, cb, bg, bb, hb16o, flag, N);
}

__global__ __launch_bounds__(256) void k_agg2(
    const unsigned* __restrict__ hwu, float* __restrict__ h,
    const int* __restrict__ cnt, const unsigned short* __restrict__ slots,
    const float* __restrict__ cb, const float* __restrict__ bg, const float* __restrict__ bb,
    uint4* __restrict__ hb16o, const int* __restrict__ flag, int N)
{
    agg_body<1, 0, 1>(hwu, h, cnt, slots, cb, bg, bb, hb16o, flag, N);
}

__global__ __launch_bounds__(256) void k_agg3(
    const unsigned* __restrict__ hwu, float* __restrict__ h,
    const int* __restrict__ cnt, const unsigned short* __restrict__ slots,
    const float* __restrict__ cb, const float* __restrict__ bg, const float* __restrict__ bb,
    uint4* __restrict__ hb16o, const int* __restrict__ flag, int N)
{
    agg_body<0, 0, 2>(hwu, h, cnt, slots, cb, bg, bb, hb16o, flag, N);
}

// ---------------- MFMA fused heads: 2D grid (y = head), bf16 gather ----------------
__global__ __launch_bounds__(256) void k_headmm(
    const uint4* __restrict__ hb16, const int* __restrict__ gidx,
    const uint4* __restrict__ p1v, const uint4* __restrict__ p2v,
    const float* __restrict__ hb1, const float* __restrict__ hg1, const float* __restrict__ hbb1,
    const float* __restrict__ hb2,
    const float* __restrict__ hW3, const float* __restrict__ hb3,
    const float* __restrict__ ob1, const float* __restrict__ og1, const float* __restrict__ obb1,
    const float* __restrict__ ob2, const float* __restrict__ og2, const float* __restrict__ obb2,
    const float* __restrict__ oW3, const float* __restrict__ ob3,
    float* __restrict__ out, int G)
{
    __shared__ __align__(16) unsigned sxg[64 * 68];
    __shared__ __align__(16) unsigned sz1u[64 * 36];
    __shared__ __align__(16) unsigned sz2u[64 * 20];
    __shared__ float sb1[64], sg1[64], sbb1[64];
    __shared__ float sb2[32], sg2[32], sbb2[32];
    __shared__ float sW3[96];
    __shared__ float sb3[3];
    __shared__ int sgi[64];

    int t = threadIdx.x;
    int gblk = blockIdx.x;
    int y = blockIdx.y;
    bool bn2 = (y == 4);
    int w = t >> 6, l = t & 63;
    int lanen = l & 15, quad = l >> 4;

    const float* b1  = bn2 ? ob1  : (hb1 + y * 64);
    const float* g1  = bn2 ? og1  : (hg1 + y * 64);
    const float* bb1 = bn2 ? obb1 : (hbb1 + y * 64);
    const float* b2  = bn2 ? ob2  : (hb2 + y * 32);
    const float* W3  = bn2 ? oW3  : (hW3 + y * 32);
    const float* b3  = bn2 ? ob3  : (hb3 + y);
    int nc3 = bn2 ? 3 : 1;

    if (t < 64){
        sb1[t] = b1[t]; sg1[t] = g1[t]; sbb1[t] = bb1[t];
        if (t < 3) sb3[t] = (t < nc3) ? b3[t] : 0.f;
    } else if (t < 96){
        int p = t - 64;
        sb2[p] = b2[p];
        sg2[p] = bn2 ? og2[p] : 1.f;
        sbb2[p] = bn2 ? obb2[p] : 0.f;
    } else if (t < 192){
        int i = t - 96;
        sW3[i] = (i < 32 * nc3) ? W3[i] : 0.f;
    } else {
        int r = t - 192;
        int g = gblk * 64 + r;
        sgi[r] = (g < G) ? gidx[g] : 0;
    }
    __syncthreads();
    for (int i = t; i < 1024; i += 256){
        int r = i >> 4, c = i & 15;
        int node = sgi[r];
        uint4 v = hb16[(size_t)node * 16 + c];
        *(uint4*)&sxg[r * 68 + c * 4] = v;
    }
    __syncthreads();

    f32x4 acc1[4] = {{0.f,0.f,0.f,0.f},{0.f,0.f,0.f,0.f},{0.f,0.f,0.f,0.f},{0.f,0.f,0.f,0.f}};
#pragma unroll
    for (int kc = 0; kc < 4; ++kc){
        U128 a;
        a.u = *(const uint4*)&sxg[(w * 16 + lanen) * 68 + kc * 16 + quad * 4];
#pragma unroll
        for (int nt = 0; nt < 4; ++nt){
            U128 bfr;
            bfr.u = p1v[((y * 4 + nt) * 4 + kc) * 64 + l];
            acc1[nt] = __builtin_amdgcn_mfma_f32_16x16x32_bf16(a.s, bfr.s, acc1[nt], 0, 0, 0);
        }
    }
    {
        unsigned short* sz1s = (unsigned short*)sz1u;
#pragma unroll
        for (int nt = 0; nt < 4; ++nt){
            int n = nt * 16 + lanen;
            float g = sg1[n], bia = sb1[n], bt = sbb1[n];
#pragma unroll
            for (int r = 0; r < 4; ++r){
                int row = w * 16 + quad * 4 + r;
                float v = g * ((acc1[nt][r] + bia) * BN_S) + bt;
                sz1s[row * 72 + n] = f2bs(fmaxf(v, 0.f));
            }
        }
    }
    __syncthreads();

    f32x4 acc2[2] = {{0.f,0.f,0.f,0.f},{0.f,0.f,0.f,0.f}};
#pragma unroll
    for (int kc = 0; kc < 2; ++kc){
        U128 a;
        a.u = *(const uint4*)&sz1u[(w * 16 + lanen) * 36 + kc * 16 + quad * 4];
#pragma unroll
        for (int nt = 0; nt < 2; ++nt){
            U128 bfr;
            bfr.u = p2v[((y * 2 + nt) * 2 + kc) * 64 + l];
            acc2[nt] = __builtin_amdgcn_mfma_f32_16x16x32_bf16(a.s, bfr.s, acc2[nt], 0, 0, 0);
        }
    }
    {
        unsigned short* sz2s = (unsigned short*)sz2u;
#pragma unroll
        for (int nt = 0; nt < 2; ++nt){
            int n = nt * 16 + lanen;
            float bia = sb2[n], g = sg2[n], bt = sbb2[n];
#pragma unroll
            for (int r = 0; r < 4; ++r){
                int row = w * 16 + quad * 4 + r;
                float v = acc2[nt][r] + bia;
                if (bn2) v = g * (v * BN_S) + bt;
                sz2s[row * 40 + n] = f2bs(fmaxf(v, 0.f));
            }
        }
    }
    __syncthreads();

    const unsigned short* sz2s = (const unsigned short*)sz2u;
    if (!bn2){
        if (t < 64){
            int g = gblk * 64 + t;
            if (g < G){
                float s = sb3[0];
#pragma unroll
                for (int p = 0; p < 32; ++p) s = fmaf(bs2f(sz2s[t * 40 + p]), sW3[p], s);
                out[(size_t)g * 7 + y] = s;
            }
        }
    } else {
        if (t < 192){
            int gl = t / 3, c = t % 3;
            int g = gblk * 64 + gl;
            if (g < G){
                float s = sb3[c];
#pragma unroll
                for (int p = 0; p < 32; ++p) s = fmaf(bs2f(sz2s[gl * 40 + p]), sW3[p * 3 + c], s);
                out[(size_t)g * 7 + 4 + c] = s;
            }
        }
    }
}

extern "C" void kernel_launch(void* const* d_in, const int* in_sizes, int n_in,
                              void* d_out, int out_size, void* d_ws, size_t ws_size,
                              hipStream_t stream)
{
    const float* x    = (const float*)d_in[0];
    const int* esrc   = (const int*)d_in[1];
    const int* edst   = (const int*)d_in[2];
    const int* gidx   = (const int*)d_in[3];
    const float* in_g = (const float*)d_in[4];
    const float* in_b = (const float*)d_in[5];
    const float* lin_W = (const float*)d_in[6];
    const float* lin_b = (const float*)d_in[7];
    const float* bn0_g = (const float*)d_in[8];
    const float* bn0_b = (const float*)d_in[9];
    const float* cW[3] = {(const float*)d_in[10], (const float*)d_in[14], (const float*)d_in[18]};
    const float* cb[3] = {(const float*)d_in[11], (const float*)d_in[15], (const float*)d_in[19]};
    const float* bg[3] = {(const float*)d_in[12], (const float*)d_in[16], (const float*)d_in[20]};
    const float* bb[3] = {(const float*)d_in[13], (const float*)d_in[17], (const float*)d_in[21]};
    const float* hW1 = (const float*)d_in[22];
    const float* hb1 = (const float*)d_in[23];
    const float* hg1 = (const float*)d_in[24];
    const float* hbb1 = (const float*)d_in[25];
    const float* hW2 = (const float*)d_in[26];
    const float* hb2 = (const float*)d_in[27];
    const float* hW3 = (const float*)d_in[28];
    const float* hb3 = (const float*)d_in[29];
    const float* oW1 = (const float*)d_in[30];
    const float* ob1 = (const float*)d_in[31];
    const float* og1 = (const float*)d_in[32];
    const float* obb1 = (const float*)d_in[33];
    const float* oW2 = (const float*)d_in[34];
    const float* ob2 = (const float*)d_in[35];
    const float* og2 = (const float*)d_in[36];
    const float* obb2 = (const float*)d_in[37];
    const float* oW3 = (const float*)d_in[38];
    const float* ob3 = (const float*)d_in[39];

    const int N = in_sizes[0] / HDIM;
    const int E = in_sizes[1];
    const int G = in_sizes[3];

    char* wsp = (char*)d_ws;
    size_t off = 0;
    auto alloc = [&](size_t bytes) -> char* {
        char* p = wsp + off;
        off = (off + bytes + 255) & ~(size_t)255;
        return p;
    };
    int* cnt      = (int*)alloc((size_t)(2 * N) * 4);   // cnt[N] then flag[N]
    int* flag     = cnt + N;
    unsigned short* slots = (unsigned short*)alloc((size_t)N * PAD * 2);
    float* hbuf   = (float*)alloc((size_t)N * HDIM * 4);
    unsigned short* hwbA = (unsigned short*)alloc((size_t)N * HDIM * 2);
    unsigned short* hwbB = (unsigned short*)alloc((size_t)N * HDIM * 2);
    unsigned short* hb16 = (unsigned short*)alloc((size_t)N * HDIM * 2);
    unsigned short* p1 = (unsigned short*)alloc(40960 * 2);
    unsigned short* p2 = (unsigned short*)alloc(10240 * 2);
    unsigned short* wf = (unsigned short*)alloc((size_t)4 * 32768 * 2);

    int gb = (N + 63) / 64;
    int nCB = (E + 255) / 256;
    int nFB = (G + 255) / 256;
    int nPB = (32768 + 51200 + 255) / 256;     // rest-prepack blocks (wf2,wf3,p1,p2)
    int prep0Tot = 32768 + 2 * N;

    // 1: minimal prefix — wf0/wf1 prepack + cnt/flag zero
    k_prep0<<<dim3((prep0Tot + 255) / 256), dim3(256), 0, stream>>>(
        lin_W, cW[0], wf, cnt, 2 * N);
    // 2: fused gemm0+gemm1 + count + flag + rest-prepack (all independent sections)
    k_cg01e<<<dim3(gb + nCB + nFB + nPB), dim3(256), 0, stream>>>(
        x, (const uint4*)wf, (const uint4*)(wf + (size_t)32768),
        in_g, in_b, lin_b, bn0_g, bn0_b, hbuf, hwbA, N, gb, nCB, nFB,
        esrc, edst, cnt, slots, E, gidx, flag, G,
        cW[1], cW[2], hW1, oW1, hW2, oW2, wf, p1, p2);
    // 3: agg layer-1 (scales gathered rows by dis[src] from cnt) -> h1 (fp32 + bf16)
    k_agg1<<<dim3((N + 3) / 4), dim3(256), 0, stream>>>(
        (const unsigned*)hwbA, hbuf, cnt, slots, cb[0], bg[0], bb[0], (uint4*)hb16, flag, N);
    // 4: gemm layer-2 (wf2 packed inside cg01e; cnt ready)
    k_gemmb<<<dim3(gb), dim3(256), 0, stream>>>(
        (const uint4*)hb16, (const uint4*)(wf + (size_t)2 * 32768), cnt, hwbB, N);
    // 5: agg layer-2 -> h2 (fp32 h write gated on flag; bf16 for all rows)
    k_agg2<<<dim3((N + 3) / 4), dim3(256), 0, stream>>>(
        (const unsigned*)hwbB, hbuf, cnt, slots, cb[1], bg[1], bb[1], (uint4*)hb16, flag, N);
    // 6: gemm layer-3
    k_gemmb<<<dim3(gb), dim3(256), 0, stream>>>(
        (const uint4*)hb16, (const uint4*)(wf + (size_t)3 * 32768), cnt, hwbA, N);
    // 7: agg layer-3 -> bf16 h3, FLAGGED ROWS ONLY (heads read only gidx nodes)
    k_agg3<<<dim3((N + 3) / 4), dim3(256), 0, stream>>>(
        (const unsigned*)hwbA, hbuf, cnt, slots, cb[2], bg[2], bb[2], (uint4*)hb16, flag, N);
    // 8: heads — 2D grid, 5 heads x 256 game-blocks
    k_headmm<<<dim3((G + 63) / 64, 5), dim3(256), 0, stream>>>(
        (const uint4*)hb16, gidx, (const uint4*)p1, (const uint4*)p2,
        hb1, hg1, hbb1, hb2, hW3, hb3,
        ob1, og1, obb1, ob2, og2, obb2, oW3, ob3,
        (float*)d_out, G);
}